// Round 11
// baseline (110.024 us; speedup 1.0000x reference)
//
#include <hip/hip_runtime.h>
#include <hip/hip_bf16.h>
#include <stdint.h>

// Problem constants
#define S_LEN   4096
#define HIDDEN  1024
#define NHEAD   16
#define NKV     4
#define HD      64
#define WINDOW  512
#define L2E     1.4426950408889634f
#define QSCALE  (0.125f * L2E)

using short8 = __attribute__((ext_vector_type(8))) short;
using f32x4  = __attribute__((ext_vector_type(4))) float;

// fp32 -> bf16, round-to-nearest-even
__device__ __forceinline__ uint16_t f2bf(float f) {
  uint32_t u = __builtin_bit_cast(uint32_t, f);
  u += 0x7fffu + ((u >> 16) & 1u);
  return (uint16_t)(u >> 16);
}
// round-to-nearest (ties up) — P values only (all >=0, bias ~2^-17)
__device__ __forceinline__ uint16_t f2bf_rn(float f) {
  uint32_t u = __builtin_bit_cast(uint32_t, f);
  return (uint16_t)((u + 0x8000u) >> 16);
}
__device__ __forceinline__ uint32_t pk2(float a, float b) {
  return (uint32_t)f2bf_rn(a) | ((uint32_t)f2bf_rn(b) << 16);
}

// async global->LDS, 16B per lane. LDS dest must be wave-uniform base + lane*16.
__device__ __forceinline__ void gld_lds16(void* lds, const void* g) {
  __builtin_amdgcn_global_load_lds(
      (const __attribute__((address_space(1))) char*)g,
      (__attribute__((address_space(3))) char*)lds, 16, 0, 0);
}

// ---------------------------------------------------------------------------
// Kernel 1: pack x, wq|wk|wv (concat rows), wo to bf16
// ---------------------------------------------------------------------------
__global__ __launch_bounds__(256) void k_tobf16(
    const float* __restrict__ x, const float* __restrict__ wq,
    const float* __restrict__ wk, const float* __restrict__ wv,
    const float* __restrict__ wo,
    uint16_t* __restrict__ xb, uint16_t* __restrict__ wqkvb,
    uint16_t* __restrict__ wob) {
  int i = blockIdx.x * 256 + threadIdx.x;  // one float4 per thread, exact grid
  const float4* src; uint16_t* dst; int off;
  if (i < 1048576)      { src = (const float4*)x;  dst = xb;                off = i; }
  else if (i < 1310720) { src = (const float4*)wq; dst = wqkvb;             off = i - 1048576; }
  else if (i < 1376256) { src = (const float4*)wk; dst = wqkvb + 1024*1024; off = i - 1310720; }
  else if (i < 1441792) { src = (const float4*)wv; dst = wqkvb + 1280*1024; off = i - 1376256; }
  else                  { src = (const float4*)wo; dst = wob;               off = i - 1441792; }
  float4 v = src[off];
  ushort4 o = { f2bf(v.x), f2bf(v.y), f2bf(v.z), f2bf(v.w) };
  *(ushort4*)(dst + (size_t)off * 4) = o;
}

// ---------------------------------------------------------------------------
// Kernel 2: QKV GEMM with fused RMSNorm + RoPE + cast + layout epilogue.
// BM=64, BN=128, BK=128 (8 K-steps -> half the barrier drains of BK=64).
// 4 waves in 2x2, wave tile 32x64 (acc[2][4]). LDS 48KB -> 3 blocks/CU.
// Flat grid 768 with XCD-pinning swizzle.
// ---------------------------------------------------------------------------
__global__ __launch_bounds__(256) void k_gemm_qkv(
    const uint16_t* __restrict__ A, const uint16_t* __restrict__ B,
    const float* __restrict__ cosb, const float* __restrict__ sinb,
    const float* __restrict__ qw, const float* __restrict__ kw,
    uint16_t* __restrict__ qout, uint16_t* __restrict__ kout,
    uint16_t* __restrict__ vtout) {
  __shared__ uint16_t As[64 * 128];
  __shared__ uint16_t Bs[128 * 128];
  const int K = 1024;
  const int t = threadIdx.x;
  const int lane = t & 63, w = t >> 6;
  const int wr = w >> 1, wc = w & 1;
  const int l16 = lane & 15, lg = lane >> 4;
  const int bid = blockIdx.x;
  const int xcd = bid & 7, idx = bid >> 3;         // idx in [0,96)
  const int bm = xcd + 8 * (idx & 7);              // [0,64)
  const int bn = idx >> 3;                         // [0,12)
  const uint16_t* Ab = A + (size_t)bm * 64 * K;
  const uint16_t* Bb = B + (size_t)bn * 128 * K;
  f32x4 acc[2][4] = {};
  for (int k0 = 0; k0 < K; k0 += 128) {
    __syncthreads();
#pragma unroll
    for (int it = 0; it < 4; ++it) {   // stage A: 64x128 = 1024 16B-chunks
      int id2 = it * 256 + t;
      int row = id2 >> 4, c8 = (id2 & 15) << 3;
      gld_lds16(&As[id2 * 8], Ab + (size_t)row * K + k0 + c8);
    }
#pragma unroll
    for (int it = 0; it < 8; ++it) {   // stage B: 128x128 = 2048 16B-chunks
      int id2 = it * 256 + t;
      int row = id2 >> 4, c8 = (id2 & 15) << 3;
      gld_lds16(&Bs[id2 * 8], Bb + (size_t)row * K + k0 + c8);
    }
    __syncthreads();
#pragma unroll
    for (int kk = 0; kk < 4; ++kk) {
      short8 af[2], bq[4];
#pragma unroll
      for (int i = 0; i < 2; ++i)
        af[i] = *(const short8*)&As[(wr * 32 + i * 16 + l16) * 128 + kk * 32 + lg * 8];
#pragma unroll
      for (int j = 0; j < 4; ++j)
        bq[j] = *(const short8*)&Bs[(wc * 64 + j * 16 + l16) * 128 + kk * 32 + lg * 8];
#pragma unroll
      for (int i = 0; i < 2; ++i)
#pragma unroll
        for (int j = 0; j < 4; ++j)
          acc[i][j] = __builtin_amdgcn_mfma_f32_16x16x32_bf16(af[i], bq[j], acc[i][j], 0, 0, 0);
    }
  }

  // ---- fused epilogue ----
  const int hg = bn * 2 + wc;   // global 64-wide head slot, uniform per wave
  if (hg >= 20) {               // V: cast + transposed store
    const int kvh = hg - 20;
#pragma unroll
    for (int i = 0; i < 2; ++i) {
      int row0 = bm * 64 + wr * 32 + i * 16 + lg * 4;
#pragma unroll
      for (int j = 0; j < 4; ++j) {
        int d = j * 16 + l16;
        ushort4 o = { f2bf(acc[i][j][0]), f2bf(acc[i][j][1]),
                      f2bf(acc[i][j][2]), f2bf(acc[i][j][3]) };
        *(ushort4*)(vtout + (size_t)(kvh * 64 + d) * S_LEN + row0) = o;
      }
    }
    return;
  }
  // Q/K: RMSNorm + RoPE
  const float* nw = (hg < 16) ? qw : kw;
  float wgt[4];
#pragma unroll
  for (int j = 0; j < 4; ++j) wgt[j] = nw[j * 16 + l16];
#pragma unroll
  for (int i = 0; i < 2; ++i) {
    int row0 = bm * 64 + wr * 32 + i * 16 + lg * 4;
    float qn[4][4];
#pragma unroll
    for (int r = 0; r < 4; ++r) {
      float ss = acc[i][0][r] * acc[i][0][r] + acc[i][1][r] * acc[i][1][r]
               + acc[i][2][r] * acc[i][2][r] + acc[i][3][r] * acc[i][3][r];
      ss += __shfl_xor(ss, 1);
      ss += __shfl_xor(ss, 2);
      ss += __shfl_xor(ss, 4);
      ss += __shfl_xor(ss, 8);
      float inv = rsqrtf(ss * (1.0f / 64.0f) + 1e-5f);
#pragma unroll
      for (int j = 0; j < 4; ++j) qn[j][r] = acc[i][j][r] * inv * wgt[j];
    }
#pragma unroll
    for (int j = 0; j < 4; ++j) {
      int d = j * 16 + l16;
#pragma unroll
      for (int r = 0; r < 4; ++r) {
        int row = row0 + r;
        float rot = (j < 2) ? -qn[j + 2][r] : qn[j - 2][r];   // rotate_half
        float o = qn[j][r] * cosb[row * 64 + d] + rot * sinb[row * 64 + d];
        if (hg < 16)
          qout[(size_t)row * HIDDEN + hg * 64 + d] = f2bf(o * QSCALE);
        else
          kout[((size_t)(hg - 16) * S_LEN + row) * 64 + d] = f2bf(o);
      }
    }
  }
}

// ---------------------------------------------------------------------------
// Kernel 4: C[M][N] = A[M][K] * B[N][K]^T — output projection (M=4096, N=1024).
// BK=128, flat grid 512, XCD-pinned.
// ---------------------------------------------------------------------------
__global__ __launch_bounds__(256) void k_gemm_bf16(
    const uint16_t* __restrict__ A, const uint16_t* __restrict__ B,
    float* __restrict__ C, int N, int K) {
  __shared__ uint16_t As[64 * 128];
  __shared__ uint16_t Bs[128 * 128];
  const int t = threadIdx.x;
  const int lane = t & 63, w = t >> 6;
  const int wr = w >> 1, wc = w & 1;
  const int l16 = lane & 15, lg = lane >> 4;
  const int bid = blockIdx.x;
  const int xcd = bid & 7, idx = bid >> 3;         // idx in [0,64)
  const int bm = xcd + 8 * (idx & 7);              // [0,64)
  const int bn = idx >> 3;                         // [0,8)
  const uint16_t* Ab = A + (size_t)bm * 64 * K;
  const uint16_t* Bb = B + (size_t)bn * 128 * K;
  f32x4 acc[2][4] = {};
  for (int k0 = 0; k0 < K; k0 += 128) {
    __syncthreads();
#pragma unroll
    for (int it = 0; it < 4; ++it) {
      int id2 = it * 256 + t;
      int row = id2 >> 4, c8 = (id2 & 15) << 3;
      gld_lds16(&As[id2 * 8], Ab + (size_t)row * K + k0 + c8);
    }
#pragma unroll
    for (int it = 0; it < 8; ++it) {
      int id2 = it * 256 + t;
      int row = id2 >> 4, c8 = (id2 & 15) << 3;
      gld_lds16(&Bs[id2 * 8], Bb + (size_t)row * K + k0 + c8);
    }
    __syncthreads();
#pragma unroll
    for (int kk = 0; kk < 4; ++kk) {
      short8 af[2], bq[4];
#pragma unroll
      for (int i = 0; i < 2; ++i)
        af[i] = *(const short8*)&As[(wr * 32 + i * 16 + l16) * 128 + kk * 32 + lg * 8];
#pragma unroll
      for (int j = 0; j < 4; ++j)
        bq[j] = *(const short8*)&Bs[(wc * 64 + j * 16 + l16) * 128 + kk * 32 + lg * 8];
#pragma unroll
      for (int i = 0; i < 2; ++i)
#pragma unroll
        for (int j = 0; j < 4; ++j)
          acc[i][j] = __builtin_amdgcn_mfma_f32_16x16x32_bf16(af[i], bq[j], acc[i][j], 0, 0, 0);
    }
  }
#pragma unroll
  for (int i = 0; i < 2; ++i) {
    int row0 = bm * 64 + wr * 32 + i * 16 + lg * 4;
#pragma unroll
    for (int j = 0; j < 4; ++j) {
      int col = bn * 128 + wc * 64 + j * 16 + l16;
#pragma unroll
      for (int r = 0; r < 4; ++r)
        C[(size_t)(row0 + r) * N + col] = acc[i][j][r];
    }
  }
}

// ---------------------------------------------------------------------------
// Kernel 3: sliding-window flash attention — round-6 compute structure,
// ONE HEAD PER BLOCK (4 waves, 256 thr), grid 1024 = 4 blocks/CU.
// Four independent 4-wave barrier groups per CU de-phase naturally, so one
// block's MFMA overlaps another's softmax/VALU (m114) — attacks the 8-wave
// lockstep that made rounds 7-10's staging tweaks null.
// T14 reg prefetch (commit -> barrier -> prefetch next), padded LDS,
// swapped QK^T 16x16, fixed-max softmax, T5 setprio.
// ---------------------------------------------------------------------------
__global__ __launch_bounds__(256) void k_attn(
    const uint16_t* __restrict__ qb,   // [S][HIDDEN], pre-scaled by QSCALE
    const uint16_t* __restrict__ kb,   // [KV][S][64]
    const uint16_t* __restrict__ vtb,  // [KV][64][S]
    const float* __restrict__ sinks,
    uint16_t* __restrict__ ao) {       // [S][HIDDEN]
  __shared__ uint16_t Kl[64][72];      // +8 pad
  __shared__ uint16_t Vl[64][72];      // V^T tile: [d][key]
  __shared__ uint16_t Pl[4][16][72];   // per-wave P: [q(16)][key(64)+pad]
  const int bid = blockIdx.x;
  const int h = bid & 15;                  // head; consecutive bids spread heads
  const int q0 = (63 - (bid >> 4)) * 64;   // long blocks first
  const int kvh = h >> 2;
  const int t = threadIdx.x;
  const int lane = t & 63, w = t >> 6;     // w = q-subtile 0..3
  const int l16 = lane & 15, lg = lane >> 4;
  const int qrow = q0 + w * 16 + l16;      // this lane's q-row

  // Q fragment, used as the B operand (n = l16 = q-row)
  short8 bq0, bq1;
  {
    const uint16_t* qp = qb + (size_t)qrow * HIDDEN + h * 64 + lg * 8;
    bq0 = *(const short8*)qp;
    bq1 = *(const short8*)(qp + 32);
  }
  float lsum = 0.f;
  f32x4 acc[4] = {};

  int kstart = q0 - WINDOW;
  if (kstart < 0) kstart = 0;

  // staging: thread t owns rows r1 = t>>3 and r1+32, chunk sc8 = (t&7)*8
  const int r1 = t >> 3, sc8 = (t & 7) << 3;
  const uint16_t* kp  = kb + ((size_t)kvh * S_LEN + r1) * 64 + sc8;
  const uint16_t* kp2 = kp + (size_t)32 * 64;
  const uint16_t* vp  = vtb + ((size_t)kvh * 64 + r1) * S_LEN + sc8;
  const uint16_t* vp2 = vp + (size_t)32 * S_LEN;
  // prologue: first tile into regs
  short8 nk0 = *(const short8*)(kp  + (size_t)kstart * 64);
  short8 nk1 = *(const short8*)(kp2 + (size_t)kstart * 64);
  short8 nv0 = *(const short8*)(vp  + kstart);
  short8 nv1 = *(const short8*)(vp2 + kstart);

  for (int k0 = kstart; k0 <= q0; k0 += 64) {
    __syncthreads();                   // previous tile fully consumed
    *(short8*)&Kl[r1][sc8]      = nk0; // commit prefetched tile
    *(short8*)&Kl[r1 + 32][sc8] = nk1;
    *(short8*)&Vl[r1][sc8]      = nv0;
    *(short8*)&Vl[r1 + 32][sc8] = nv1;
    __syncthreads();
    if (k0 + 64 <= q0) {               // T14: issue next-tile loads NOW
      nk0 = *(const short8*)(kp  + (size_t)(k0 + 64) * 64);
      nk1 = *(const short8*)(kp2 + (size_t)(k0 + 64) * 64);
      nv0 = *(const short8*)(vp  + k0 + 64);
      nv1 = *(const short8*)(vp2 + k0 + 64);
    }

    // S^T = K Q^T: D[m=key][n=q]
    f32x4 st[4] = {};
    __builtin_amdgcn_s_setprio(1);
#pragma unroll
    for (int c = 0; c < 4; ++c) {
      short8 ak0 = *(const short8*)&Kl[c * 16 + l16][lg * 8];
      short8 ak1 = *(const short8*)&Kl[c * 16 + l16][32 + lg * 8];
      st[c] = __builtin_amdgcn_mfma_f32_16x16x32_bf16(ak0, bq0, st[c], 0, 0, 0);
      st[c] = __builtin_amdgcn_mfma_f32_16x16x32_bf16(ak1, bq1, st[c], 0, 0, 0);
    }
    __builtin_amdgcn_s_setprio(0);

    // key = k0 + c*16 + lg*4 + r; q-row = qrow (lane-local). Mask edge tiles.
    float p[4][4];
    if (k0 == q0 || k0 == q0 - WINDOW) {
#pragma unroll
      for (int c = 0; c < 4; ++c) {
        int keyb = k0 + c * 16 + lg * 4;
#pragma unroll
        for (int r = 0; r < 4; ++r) {
          int key = keyb + r;
          bool ok = (key <= qrow) && (key + WINDOW > qrow);
          p[c][r] = ok ? exp2f(st[c][r]) : 0.f;
        }
      }
    } else {
#pragma unroll
      for (int c = 0; c < 4; ++c)
#pragma unroll
        for (int r = 0; r < 4; ++r)
          p[c][r] = exp2f(st[c][r]);
    }
#pragma unroll
    for (int c = 0; c < 4; ++c)
      lsum += (p[c][0] + p[c][1]) + (p[c][2] + p[c][3]);

    // pack P (keys consecutive in r) -> [q][key] LDS layout, 8B stores
#pragma unroll
    for (int c = 0; c < 4; ++c) {
      uint2 pw = { pk2(p[c][0], p[c][1]), pk2(p[c][2], p[c][3]) };
      *(uint2*)&Pl[w][l16][c * 16 + lg * 4] = pw;
    }
    asm volatile("s_waitcnt lgkmcnt(0)" ::: "memory");
    short8 pa0 = *(const short8*)&Pl[w][l16][lg * 8];
    short8 pa1 = *(const short8*)&Pl[w][l16][32 + lg * 8];
    __builtin_amdgcn_s_setprio(1);
#pragma unroll
    for (int dt = 0; dt < 4; ++dt) {
      short8 bv0 = *(const short8*)&Vl[dt * 16 + l16][lg * 8];
      short8 bv1 = *(const short8*)&Vl[dt * 16 + l16][32 + lg * 8];
      acc[dt] = __builtin_amdgcn_mfma_f32_16x16x32_bf16(pa0, bv0, acc[dt], 0, 0, 0);
      acc[dt] = __builtin_amdgcn_mfma_f32_16x16x32_bf16(pa1, bv1, acc[dt], 0, 0, 0);
    }
    __builtin_amdgcn_s_setprio(0);
  }

  // lsum: reduce across the 4 lg-groups (lanes sharing l16), add sink
  lsum += __shfl_xor(lsum, 16);
  lsum += __shfl_xor(lsum, 32);
  float sk = exp2f(sinks[h] * L2E);
  float inv = 1.0f / (lsum + sk);     // lane (l16,lg) holds inv for local row l16
  // acc rows are local row lg*4+r -> fetch inv from lane (lg*4+r)
#pragma unroll
  for (int r = 0; r < 4; ++r) {
    float rd = __shfl(inv, lg * 4 + r);
    int row = q0 + w * 16 + lg * 4 + r;
#pragma unroll
    for (int dt = 0; dt < 4; ++dt)
      ao[(size_t)row * HIDDEN + h * 64 + dt * 16 + l16] = f2bf(acc[dt][r] * rd);
  }
}

// ---------------------------------------------------------------------------
// Launch. Workspace layout (~33 MB of d_ws):
//   [0,8M)    xb      bf16 x            [4096][1024]
//   [8,11M)   wqkvb   bf16 wq|wk|wv     [1536][1024]
//   [11,13M)  wob     bf16 wo           [1024][1024]
//   [13,21M)  qsc     bf16 q (scaled)   [4096][1024]
//   [21,23M)  kbf     bf16 k            [4][4096][64]
//   [23,25M)  vtb     bf16 v^T          [4][64][4096]
//   [25,33M)  aob     bf16 attn out     [4096][1024]
// ---------------------------------------------------------------------------
extern "C" void kernel_launch(void* const* d_in, const int* in_sizes, int n_in,
                              void* d_out, int out_size, void* d_ws, size_t ws_size,
                              hipStream_t stream) {
  const float* x     = (const float*)d_in[0];
  const float* cosb  = (const float*)d_in[1];
  const float* sinb  = (const float*)d_in[2];
  const float* wq    = (const float*)d_in[3];
  const float* wk    = (const float*)d_in[4];
  const float* wv    = (const float*)d_in[5];
  const float* wo    = (const float*)d_in[6];
  const float* qnw   = (const float*)d_in[7];
  const float* knw   = (const float*)d_in[8];
  const float* sinks = (const float*)d_in[9];
  float* out = (float*)d_out;

  char* ws = (char*)d_ws;
  uint16_t* xb    = (uint16_t*)(ws);
  uint16_t* wqkvb = (uint16_t*)(ws + (8ll  << 20));
  uint16_t* wob   = (uint16_t*)(ws + (11ll << 20));
  uint16_t* qsc   = (uint16_t*)(ws + (13ll << 20));
  uint16_t* kbf   = (uint16_t*)(ws + (21ll << 20));
  uint16_t* vtb   = (uint16_t*)(ws + (23ll << 20));
  uint16_t* aob   = (uint16_t*)(ws + (25ll << 20));

  k_tobf16  <<<6656, 256, 0, stream>>>(x, wq, wk, wv, wo, xb, wqkvb, wob);
  k_gemm_qkv<<<768, 256, 0, stream>>>(xb, wqkvb, cosb, sinb, qnw, knw,
                                      qsc, kbf, vtb);
  k_attn    <<<1024, 256, 0, stream>>>(qsc, kbf, vtb, sinks, aob);
  k_gemm_bf16<<<512, 256, 0, stream>>>(aob, wob, out, 1024, 1024);
}

// Round 12
// 88.161 us; speedup vs baseline: 1.2480x; 1.2480x over previous
//
#include <hip/hip_runtime.h>
#include <hip/hip_bf16.h>
#include <stdint.h>

// Problem constants
#define S_LEN   4096
#define HIDDEN  1024
#define NHEAD   16
#define NKV     4
#define HD      64
#define WINDOW  512
#define L2E     1.4426950408889634f
#define QSCALE  (0.125f * L2E)

using short8 = __attribute__((ext_vector_type(8))) short;
using f32x4  = __attribute__((ext_vector_type(4))) float;
using f32x16 = __attribute__((ext_vector_type(16))) float;

// fp32 -> bf16, round-to-nearest-even
__device__ __forceinline__ uint16_t f2bf(float f) {
  uint32_t u = __builtin_bit_cast(uint32_t, f);
  u += 0x7fffu + ((u >> 16) & 1u);
  return (uint16_t)(u >> 16);
}
// round-to-nearest (ties up) — P values only (all >=0, bias ~2^-17)
__device__ __forceinline__ uint16_t f2bf_rn(float f) {
  uint32_t u = __builtin_bit_cast(uint32_t, f);
  return (uint16_t)((u + 0x8000u) >> 16);
}
__device__ __forceinline__ uint32_t pk2(float a, float b) {
  return (uint32_t)f2bf_rn(a) | ((uint32_t)f2bf_rn(b) << 16);
}

// async global->LDS, 16B per lane. LDS dest must be wave-uniform base + lane*16.
__device__ __forceinline__ void gld_lds16(void* lds, const void* g) {
  __builtin_amdgcn_global_load_lds(
      (const __attribute__((address_space(1))) char*)g,
      (__attribute__((address_space(3))) char*)lds, 16, 0, 0);
}

// ---------------------------------------------------------------------------
// Kernel 1: pack x, wq|wk|wv (concat rows), wo to bf16
// ---------------------------------------------------------------------------
__global__ __launch_bounds__(256) void k_tobf16(
    const float* __restrict__ x, const float* __restrict__ wq,
    const float* __restrict__ wk, const float* __restrict__ wv,
    const float* __restrict__ wo,
    uint16_t* __restrict__ xb, uint16_t* __restrict__ wqkvb,
    uint16_t* __restrict__ wob) {
  int i = blockIdx.x * 256 + threadIdx.x;  // one float4 per thread, exact grid
  const float4* src; uint16_t* dst; int off;
  if (i < 1048576)      { src = (const float4*)x;  dst = xb;                off = i; }
  else if (i < 1310720) { src = (const float4*)wq; dst = wqkvb;             off = i - 1048576; }
  else if (i < 1376256) { src = (const float4*)wk; dst = wqkvb + 1024*1024; off = i - 1310720; }
  else if (i < 1441792) { src = (const float4*)wv; dst = wqkvb + 1280*1024; off = i - 1376256; }
  else                  { src = (const float4*)wo; dst = wob;               off = i - 1441792; }
  float4 v = src[off];
  ushort4 o = { f2bf(v.x), f2bf(v.y), f2bf(v.z), f2bf(v.w) };
  *(ushort4*)(dst + (size_t)off * 4) = o;
}

// ---------------------------------------------------------------------------
// Kernel 2: QKV GEMM with fused RMSNorm + RoPE + cast + layout epilogue.
// BM=64, BN=128, BK=64 (r9 version — BK=128 regressed, 16.5M bank conflicts).
// 4 waves in 2x2, wave tile 32x64 (acc[2][4]). Flat grid 768, XCD swizzle.
// ---------------------------------------------------------------------------
__global__ __launch_bounds__(256) void k_gemm_qkv(
    const uint16_t* __restrict__ A, const uint16_t* __restrict__ B,
    const float* __restrict__ cosb, const float* __restrict__ sinb,
    const float* __restrict__ qw, const float* __restrict__ kw,
    uint16_t* __restrict__ qout, uint16_t* __restrict__ kout,
    uint16_t* __restrict__ vtout) {
  __shared__ uint16_t As[64 * 64];
  __shared__ uint16_t Bs[128 * 64];
  const int K = 1024;
  const int t = threadIdx.x;
  const int lane = t & 63, w = t >> 6;
  const int wr = w >> 1, wc = w & 1;
  const int l16 = lane & 15, lg = lane >> 4;
  const int bid = blockIdx.x;
  const int xcd = bid & 7, idx = bid >> 3;         // idx in [0,96)
  const int bm = xcd + 8 * (idx & 7);              // [0,64)
  const int bn = idx >> 3;                         // [0,12)
  const uint16_t* Ab = A + (size_t)bm * 64 * K;
  const uint16_t* Bb = B + (size_t)bn * 128 * K;
  f32x4 acc[2][4] = {};
  for (int k0 = 0; k0 < K; k0 += 64) {
    __syncthreads();
    {  // stage A: 64x64 = 512 16B-chunks -> 2/thread
      int row = t >> 3, c8 = (t & 7) << 3;
      gld_lds16(&As[t * 8], Ab + (size_t)row * K + k0 + c8);
      int t2 = t + 256, row2 = t2 >> 3, c82 = (t2 & 7) << 3;
      gld_lds16(&As[t2 * 8], Ab + (size_t)row2 * K + k0 + c82);
    }
#pragma unroll
    for (int it = 0; it < 4; ++it) {  // stage B: 128x64 -> 4/thread
      int idx2 = it * 256 + t;
      int row = idx2 >> 3, c8 = (idx2 & 7) << 3;
      gld_lds16(&Bs[idx2 * 8], Bb + (size_t)row * K + k0 + c8);
    }
    __syncthreads();
#pragma unroll
    for (int kk = 0; kk < 2; ++kk) {
      short8 af[2], bq[4];
#pragma unroll
      for (int i = 0; i < 2; ++i)
        af[i] = *(const short8*)&As[(wr * 32 + i * 16 + l16) * 64 + kk * 32 + lg * 8];
#pragma unroll
      for (int j = 0; j < 4; ++j)
        bq[j] = *(const short8*)&Bs[(wc * 64 + j * 16 + l16) * 64 + kk * 32 + lg * 8];
#pragma unroll
      for (int i = 0; i < 2; ++i)
#pragma unroll
        for (int j = 0; j < 4; ++j)
          acc[i][j] = __builtin_amdgcn_mfma_f32_16x16x32_bf16(af[i], bq[j], acc[i][j], 0, 0, 0);
    }
  }

  // ---- fused epilogue ----
  const int hg = bn * 2 + wc;   // global 64-wide head slot, uniform per wave
  if (hg >= 20) {               // V: cast + transposed store
    const int kvh = hg - 20;
#pragma unroll
    for (int i = 0; i < 2; ++i) {
      int row0 = bm * 64 + wr * 32 + i * 16 + lg * 4;
#pragma unroll
      for (int j = 0; j < 4; ++j) {
        int d = j * 16 + l16;
        ushort4 o = { f2bf(acc[i][j][0]), f2bf(acc[i][j][1]),
                      f2bf(acc[i][j][2]), f2bf(acc[i][j][3]) };
        *(ushort4*)(vtout + (size_t)(kvh * 64 + d) * S_LEN + row0) = o;
      }
    }
    return;
  }
  // Q/K: RMSNorm + RoPE
  const float* nw = (hg < 16) ? qw : kw;
  float wgt[4];
#pragma unroll
  for (int j = 0; j < 4; ++j) wgt[j] = nw[j * 16 + l16];
#pragma unroll
  for (int i = 0; i < 2; ++i) {
    int row0 = bm * 64 + wr * 32 + i * 16 + lg * 4;
    float qn[4][4];
#pragma unroll
    for (int r = 0; r < 4; ++r) {
      float ss = acc[i][0][r] * acc[i][0][r] + acc[i][1][r] * acc[i][1][r]
               + acc[i][2][r] * acc[i][2][r] + acc[i][3][r] * acc[i][3][r];
      ss += __shfl_xor(ss, 1);
      ss += __shfl_xor(ss, 2);
      ss += __shfl_xor(ss, 4);
      ss += __shfl_xor(ss, 8);
      float inv = rsqrtf(ss * (1.0f / 64.0f) + 1e-5f);
#pragma unroll
      for (int j = 0; j < 4; ++j) qn[j][r] = acc[i][j][r] * inv * wgt[j];
    }
#pragma unroll
    for (int j = 0; j < 4; ++j) {
      int d = j * 16 + l16;
#pragma unroll
      for (int r = 0; r < 4; ++r) {
        int row = row0 + r;
        float rot = (j < 2) ? -qn[j + 2][r] : qn[j - 2][r];   // rotate_half
        float o = qn[j][r] * cosb[row * 64 + d] + rot * sinb[row * 64 + d];
        if (hg < 16)
          qout[(size_t)row * HIDDEN + hg * 64 + d] = f2bf(o * QSCALE);
        else
          kout[((size_t)(hg - 16) * S_LEN + row) * 64 + d] = f2bf(o);
      }
    }
  }
}

// ---------------------------------------------------------------------------
// Kernel 4: C[M][N] = A[M][K] * B[N][K]^T — output projection (M=4096, N=1024).
// BK=64 (r9 version), flat grid 512, XCD-pinned.
// ---------------------------------------------------------------------------
__global__ __launch_bounds__(256) void k_gemm_bf16(
    const uint16_t* __restrict__ A, const uint16_t* __restrict__ B,
    float* __restrict__ C, int N, int K) {
  __shared__ uint16_t As[64 * 64];
  __shared__ uint16_t Bs[128 * 64];
  const int t = threadIdx.x;
  const int lane = t & 63, w = t >> 6;
  const int wr = w >> 1, wc = w & 1;
  const int l16 = lane & 15, lg = lane >> 4;
  const int bid = blockIdx.x;
  const int xcd = bid & 7, idx = bid >> 3;         // idx in [0,64)
  const int bm = xcd + 8 * (idx & 7);              // [0,64)
  const int bn = idx >> 3;                         // [0,8)
  const uint16_t* Ab = A + (size_t)bm * 64 * K;
  const uint16_t* Bb = B + (size_t)bn * 128 * K;
  f32x4 acc[2][4] = {};
  for (int k0 = 0; k0 < K; k0 += 64) {
    __syncthreads();
    {
      int row = t >> 3, c8 = (t & 7) << 3;
      gld_lds16(&As[t * 8], Ab + (size_t)row * K + k0 + c8);
      int t2 = t + 256, row2 = t2 >> 3, c82 = (t2 & 7) << 3;
      gld_lds16(&As[t2 * 8], Ab + (size_t)row2 * K + k0 + c82);
    }
#pragma unroll
    for (int it = 0; it < 4; ++it) {
      int idx2 = it * 256 + t;
      int row = idx2 >> 3, c8 = (idx2 & 7) << 3;
      gld_lds16(&Bs[idx2 * 8], Bb + (size_t)row * K + k0 + c8);
    }
    __syncthreads();
#pragma unroll
    for (int kk = 0; kk < 2; ++kk) {
      short8 af[2], bq[4];
#pragma unroll
      for (int i = 0; i < 2; ++i)
        af[i] = *(const short8*)&As[(wr * 32 + i * 16 + l16) * 64 + kk * 32 + lg * 8];
#pragma unroll
      for (int j = 0; j < 4; ++j)
        bq[j] = *(const short8*)&Bs[(wc * 64 + j * 16 + l16) * 64 + kk * 32 + lg * 8];
#pragma unroll
      for (int i = 0; i < 2; ++i)
#pragma unroll
        for (int j = 0; j < 4; ++j)
          acc[i][j] = __builtin_amdgcn_mfma_f32_16x16x32_bf16(af[i], bq[j], acc[i][j], 0, 0, 0);
    }
  }
#pragma unroll
  for (int i = 0; i < 2; ++i) {
    int row0 = bm * 64 + wr * 32 + i * 16 + lg * 4;
#pragma unroll
    for (int j = 0; j < 4; ++j) {
      int col = bn * 128 + wc * 64 + j * 16 + l16;
#pragma unroll
      for (int r = 0; r < 4; ++r)
        C[(size_t)(row0 + r) * N + col] = acc[i][j][r];
    }
  }
}

// ---------------------------------------------------------------------------
// Kernel 3: sliding-window flash attention — 32x32 MFMA + in-register P
// (r5/r7-verified math) + KEY-SPLIT for TLP.
// Block = 64 q-rows x 2 heads x 2 key-halves = 8 waves (512 thr); grid 512
// = 2 blocks/CU = 16 waves/CU. Wave w: kh=w&1 (key half), qs=(w>>1)&1
// (32-row q-subtile), hd=w>>2 (head of pair). Each wave covers HALF the key
// window; acc/lsum are linear under fixed-max softmax -> merged via LDS at
// the end. 32x32 waves read K/V fragments once per tile for 2x the q-rows
// of the 16x16 structure and keep P in registers: block-tile LDS ops drop
// ~160 -> ~80 (the measured bottleneck).
// Staging: r6's proven commit/barrier/prefetch pattern, both half-tiles per
// step (steps = ceil(nt/2)).
// ---------------------------------------------------------------------------
__global__ __launch_bounds__(512) void k_attn(
    const uint16_t* __restrict__ qb,   // [S][HIDDEN], pre-scaled by QSCALE
    const uint16_t* __restrict__ kb,   // [KV][S][64]
    const uint16_t* __restrict__ vtb,  // [KV][64][S]
    const float* __restrict__ sinks,
    uint16_t* __restrict__ ao) {       // [S][HIDDEN]
  __shared__ __align__(16) char smem[36864];
  auto Kl = (uint16_t(*)[64][72])(smem);           // Kl[kh][key][d] (+8 pad)
  auto Vl = (uint16_t(*)[64][72])(smem + 18432);   // Vl[kh][d][key] (+8 pad)
  float* Ms = (float*)smem;                        // merge overlay [4][64][33]

  const int bid = blockIdx.x;
  const int hp = bid & 7;                  // head-pair
  const int q0 = (63 - (bid >> 3)) * 64;   // long blocks first
  const int kvh = hp >> 1;
  const int t = threadIdx.x;
  const int lane = t & 63, w = t >> 6;
  const int kh = w & 1, qs = (w >> 1) & 1, hd = w >> 2;
  const int h = kvh * 4 + (hp & 1) * 2 + hd;
  const int qbase = q0 + qs * 32;
  const int l32 = lane & 31, hi = lane >> 5;
  const int qrow = qbase + l32;            // this lane's q-row

  // Q fragments (B operand): bq[s] = Q[qrow][h*64 + s*16 + hi*8 .. +7]
  short8 bq[4];
  {
    const uint16_t* qp = qb + (size_t)qrow * HIDDEN + h * 64 + hi * 8;
    bq[0] = *(const short8*)(qp);
    bq[1] = *(const short8*)(qp + 16);
    bq[2] = *(const short8*)(qp + 32);
    bq[3] = *(const short8*)(qp + 48);
  }

  int kstart = q0 - WINDOW;
  if (kstart < 0) kstart = 0;
  const int nt = ((q0 - kstart) >> 6) + 1;   // 1..9 tiles in window
  const int n0 = nt >> 1;                    // tiles in half0 (0..4)
  const int n1 = nt - n0;                    // tiles in half1 (1..5), = #steps

  // staging: thread t owns row r1 = t>>3, chunk sc8 = (t&7)*8 of each tile
  const int r1 = t >> 3, sc8 = (t & 7) << 3;
  const uint16_t* kpb = kb + ((size_t)kvh * S_LEN + r1) * 64 + sc8;   // +key*64
  const uint16_t* vpb = vtb + ((size_t)kvh * 64 + r1) * S_LEN + sc8;  // +key
  short8 nk0, nv0, nk1, nv1;
  if (n0 > 0) {
    nk0 = *(const short8*)(kpb + (size_t)kstart * 64);
    nv0 = *(const short8*)(vpb + kstart);
  }
  {
    int kt1 = kstart + n0 * 64;
    nk1 = *(const short8*)(kpb + (size_t)kt1 * 64);
    nv1 = *(const short8*)(vpb + kt1);
  }

  f32x16 acc0 = {}, acc1 = {};
  float lsum = 0.f;

  for (int s = 0; s < n1; ++s) {
    __syncthreads();                       // prior tile reads done
    if (s < n0) {                          // commit half0 tile s
      *(short8*)&Kl[0][r1][sc8] = nk0;
      *(short8*)&Vl[0][r1][sc8] = nv0;
    }
    *(short8*)&Kl[1][r1][sc8] = nk1;       // commit half1 tile n0+s
    *(short8*)&Vl[1][r1][sc8] = nv1;
    __syncthreads();
    if (s + 1 < n0) {                      // prefetch next half0 tile
      int kt = kstart + (s + 1) * 64;
      nk0 = *(const short8*)(kpb + (size_t)kt * 64);
      nv0 = *(const short8*)(vpb + kt);
    }
    if (s + 1 < n1) {                      // prefetch next half1 tile
      int kt = kstart + (n0 + s + 1) * 64;
      nk1 = *(const short8*)(kpb + (size_t)kt * 64);
      nv1 = *(const short8*)(vpb + kt);
    }

    if (kh == 0 && s >= n0) continue;      // half0 exhausted (wave-uniform)
    const int k0 = kstart + (kh ? (n0 + s) : s) * 64;
    const bool edge = (k0 == q0) || (k0 == q0 - WINDOW);

#pragma unroll
    for (int c = 0; c < 2; ++c) {          // two 32-key subtiles
      // S^T = K Q^T: D[key][q]; A = K from LDS
      f32x16 st = {};
      __builtin_amdgcn_s_setprio(1);
#pragma unroll
      for (int s4 = 0; s4 < 4; ++s4) {
        short8 ak = *(const short8*)&Kl[kh][c * 32 + l32][s4 * 16 + hi * 8];
        st = __builtin_amdgcn_mfma_f32_32x32x16_bf16(ak, bq[s4], st, 0, 0, 0);
      }
      __builtin_amdgcn_s_setprio(0);
      // softmax: p = exp2(st); key = k0 + c*32 + 4*hi + (r&3) + 8*(r>>2)
      float pp[16];
      if (edge) {
#pragma unroll
        for (int r = 0; r < 16; ++r) {
          int key = k0 + c * 32 + 4 * hi + (r & 3) + 8 * (r >> 2);
          bool ok = (key <= qrow) && (key + WINDOW > qrow);
          pp[r] = ok ? exp2f(st[r]) : 0.f;
        }
      } else {
#pragma unroll
        for (int r = 0; r < 16; ++r) pp[r] = exp2f(st[r]);
      }
#pragma unroll
      for (int r = 0; r < 16; ++r) lsum += pp[r];
      // pack to bf16 pairs
      uint32_t wvp[8];
#pragma unroll
      for (int i = 0; i < 8; ++i) wvp[i] = pk2(pp[2 * i], pp[2 * i + 1]);
      // PV: two 16-key steps; A-frag rebuilt in-register (r5/r7-verified)
#pragma unroll
      for (int half = 0; half < 2; ++half) {
        uint32_t x0 = wvp[half * 4 + 0], x1 = wvp[half * 4 + 1];
        uint32_t x2 = wvp[half * 4 + 2], x3 = wvp[half * 4 + 3];
        uint32_t p0 = (uint32_t)__shfl_xor((int)x0, 32);
        uint32_t p1 = (uint32_t)__shfl_xor((int)x1, 32);
        uint32_t p2 = (uint32_t)__shfl_xor((int)x2, 32);
        uint32_t p3 = (uint32_t)__shfl_xor((int)x3, 32);
        uint4 au = { hi ? p2 : x0, hi ? p3 : x1, hi ? x2 : p0, hi ? x3 : p1 };
        short8 pa = __builtin_bit_cast(short8, au);
        short8 bv0 = *(const short8*)&Vl[kh][l32][c * 32 + half * 16 + hi * 8];
        short8 bv1 = *(const short8*)&Vl[kh][32 + l32][c * 32 + half * 16 + hi * 8];
        __builtin_amdgcn_s_setprio(1);
        acc0 = __builtin_amdgcn_mfma_f32_32x32x16_bf16(pa, bv0, acc0, 0, 0, 0);
        acc1 = __builtin_amdgcn_mfma_f32_32x32x16_bf16(pa, bv1, acc1, 0, 0, 0);
        __builtin_amdgcn_s_setprio(0);
      }
    }
  }

  // per-lane q-row sum over this wave's keys (both hi halves)
  lsum += __shfl_xor(lsum, 32);

  // merge the two key-half waves of each (hd,qs) pair via LDS overlay
  __syncthreads();                         // all K/V reads done; smem reusable
  const int pid = w >> 1;                  // 0..3, same for kh=0/1 partners
  if (kh == 1) {
    float* m = &Ms[(size_t)(pid * 64 + lane) * 33];
#pragma unroll
    for (int r = 0; r < 16; ++r) { m[r] = acc0[r]; m[16 + r] = acc1[r]; }
    m[32] = lsum;
  }
  __syncthreads();
  if (kh == 0) {
    const float* m = &Ms[(size_t)(pid * 64 + lane) * 33];
#pragma unroll
    for (int r = 0; r < 16; ++r) { acc0[r] += m[r]; acc1[r] += m[16 + r]; }
    lsum += m[32];
    float inv = 1.0f / (lsum + exp2f(sinks[h] * L2E));  // lane holds q = l32
    // acc rows: q-local = (r&3) + 8*(r>>2) + 4*hi; cols: d = {0,32} + l32
#pragma unroll
    for (int r = 0; r < 16; ++r) {
      int rloc = (r & 3) + 8 * (r >> 2) + 4 * hi;
      float rd = __shfl(inv, rloc);
      size_t base = (size_t)(qbase + rloc) * HIDDEN + h * 64 + l32;
      ao[base]      = f2bf(acc0[r] * rd);
      ao[base + 32] = f2bf(acc1[r] * rd);
    }
  }
}

// ---------------------------------------------------------------------------
// Launch. Workspace layout (~33 MB of d_ws):
//   [0,8M)    xb      bf16 x            [4096][1024]
//   [8,11M)   wqkvb   bf16 wq|wk|wv     [1536][1024]
//   [11,13M)  wob     bf16 wo           [1024][1024]
//   [13,21M)  qsc     bf16 q (scaled)   [4096][1024]
//   [21,23M)  kbf     bf16 k            [4][4096][64]
//   [23,25M)  vtb     bf16 v^T          [4][64][4096]
//   [25,33M)  aob     bf16 attn out     [4096][1024]
// ---------------------------------------------------------------------------
extern "C" void kernel_launch(void* const* d_in, const int* in_sizes, int n_in,
                              void* d_out, int out_size, void* d_ws, size_t ws_size,
                              hipStream_t stream) {
  const float* x     = (const float*)d_in[0];
  const float* cosb  = (const float*)d_in[1];
  const float* sinb  = (const float*)d_in[2];
  const float* wq    = (const float*)d_in[3];
  const float* wk    = (const float*)d_in[4];
  const float* wv    = (const float*)d_in[5];
  const float* wo    = (const float*)d_in[6];
  const float* qnw   = (const float*)d_in[7];
  const float* knw   = (const float*)d_in[8];
  const float* sinks = (const float*)d_in[9];
  float* out = (float*)d_out;

  char* ws = (char*)d_ws;
  uint16_t* xb    = (uint16_t*)(ws);
  uint16_t* wqkvb = (uint16_t*)(ws + (8ll  << 20));
  uint16_t* wob   = (uint16_t*)(ws + (11ll << 20));
  uint16_t* qsc   = (uint16_t*)(ws + (13ll << 20));
  uint16_t* kbf   = (uint16_t*)(ws + (21ll << 20));
  uint16_t* vtb   = (uint16_t*)(ws + (23ll << 20));
  uint16_t* aob   = (uint16_t*)(ws + (25ll << 20));

  k_tobf16  <<<6656, 256, 0, stream>>>(x, wq, wk, wv, wo, xb, wqkvb, wob);
  k_gemm_qkv<<<768, 256, 0, stream>>>(xb, wqkvb, cosb, sinb, qnw, knw,
                                      qsc, kbf, vtb);
  k_attn    <<<512, 512, 0, stream>>>(qsc, kbf, vtb, sinks, aob);
  k_gemm_bf16<<<512, 256, 0, stream>>>(aob, wob, out, 1024, 1024);
}

// Round 13
// 81.202 us; speedup vs baseline: 1.3549x; 1.0857x over previous
//
#include <hip/hip_runtime.h>
#include <hip/hip_bf16.h>
#include <stdint.h>

// Problem constants
#define S_LEN   4096
#define HIDDEN  1024
#define NHEAD   16
#define NKV     4
#define HD      64
#define WINDOW  512
#define L2E     1.4426950408889634f
#define QSCALE  (0.125f * L2E)

using short8 = __attribute__((ext_vector_type(8))) short;
using f32x4  = __attribute__((ext_vector_type(4))) float;

// fp32 -> bf16, round-to-nearest-even
__device__ __forceinline__ uint16_t f2bf(float f) {
  uint32_t u = __builtin_bit_cast(uint32_t, f);
  u += 0x7fffu + ((u >> 16) & 1u);
  return (uint16_t)(u >> 16);
}
// round-to-nearest (ties up) — P values only (all >=0, bias ~2^-17)
__device__ __forceinline__ uint16_t f2bf_rn(float f) {
  uint32_t u = __builtin_bit_cast(uint32_t, f);
  return (uint16_t)((u + 0x8000u) >> 16);
}
__device__ __forceinline__ uint32_t pk2(float a, float b) {
  return (uint32_t)f2bf_rn(a) | ((uint32_t)f2bf_rn(b) << 16);
}

// async global->LDS, 16B per lane. LDS dest must be wave-uniform base + lane*16.
__device__ __forceinline__ void gld_lds16(void* lds, const void* g) {
  __builtin_amdgcn_global_load_lds(
      (const __attribute__((address_space(1))) char*)g,
      (__attribute__((address_space(3))) char*)lds, 16, 0, 0);
}

// ---------------------------------------------------------------------------
// Kernel 1: pack x, wq|wk|wv (concat rows), wo to bf16
// ---------------------------------------------------------------------------
__global__ __launch_bounds__(256) void k_tobf16(
    const float* __restrict__ x, const float* __restrict__ wq,
    const float* __restrict__ wk, const float* __restrict__ wv,
    const float* __restrict__ wo,
    uint16_t* __restrict__ xb, uint16_t* __restrict__ wqkvb,
    uint16_t* __restrict__ wob) {
  int i = blockIdx.x * 256 + threadIdx.x;  // one float4 per thread, exact grid
  const float4* src; uint16_t* dst; int off;
  if (i < 1048576)      { src = (const float4*)x;  dst = xb;                off = i; }
  else if (i < 1310720) { src = (const float4*)wq; dst = wqkvb;             off = i - 1048576; }
  else if (i < 1376256) { src = (const float4*)wk; dst = wqkvb + 1024*1024; off = i - 1310720; }
  else if (i < 1441792) { src = (const float4*)wv; dst = wqkvb + 1280*1024; off = i - 1376256; }
  else                  { src = (const float4*)wo; dst = wob;               off = i - 1441792; }
  float4 v = src[off];
  ushort4 o = { f2bf(v.x), f2bf(v.y), f2bf(v.z), f2bf(v.w) };
  *(ushort4*)(dst + (size_t)off * 4) = o;
}

// ---------------------------------------------------------------------------
// Kernel 2: QKV GEMM with fused RMSNorm + RoPE + cast + layout epilogue.
// BM=64, BN=128, BK=64; 4 waves in 2x2, wave tile 32x64 (acc[2][4]).
// Flat grid 768 with XCD-pinning swizzle.
// ---------------------------------------------------------------------------
__global__ __launch_bounds__(256) void k_gemm_qkv(
    const uint16_t* __restrict__ A, const uint16_t* __restrict__ B,
    const float* __restrict__ cosb, const float* __restrict__ sinb,
    const float* __restrict__ qw, const float* __restrict__ kw,
    uint16_t* __restrict__ qout, uint16_t* __restrict__ kout,
    uint16_t* __restrict__ vtout) {
  __shared__ uint16_t As[64 * 64];
  __shared__ uint16_t Bs[128 * 64];
  const int K = 1024;
  const int t = threadIdx.x;
  const int lane = t & 63, w = t >> 6;
  const int wr = w >> 1, wc = w & 1;
  const int l16 = lane & 15, lg = lane >> 4;
  const int bid = blockIdx.x;
  const int xcd = bid & 7, idx = bid >> 3;         // idx in [0,96)
  const int bm = xcd + 8 * (idx & 7);              // [0,64)
  const int bn = idx >> 3;                         // [0,12)
  const uint16_t* Ab = A + (size_t)bm * 64 * K;
  const uint16_t* Bb = B + (size_t)bn * 128 * K;
  f32x4 acc[2][4] = {};
  for (int k0 = 0; k0 < K; k0 += 64) {
    __syncthreads();
    {  // stage A: 64x64 = 512 16B-chunks -> 2/thread
      int row = t >> 3, c8 = (t & 7) << 3;
      gld_lds16(&As[t * 8], Ab + (size_t)row * K + k0 + c8);
      int t2 = t + 256, row2 = t2 >> 3, c82 = (t2 & 7) << 3;
      gld_lds16(&As[t2 * 8], Ab + (size_t)row2 * K + k0 + c82);
    }
#pragma unroll
    for (int it = 0; it < 4; ++it) {  // stage B: 128x64 -> 4/thread
      int idx2 = it * 256 + t;
      int row = idx2 >> 3, c8 = (idx2 & 7) << 3;
      gld_lds16(&Bs[idx2 * 8], Bb + (size_t)row * K + k0 + c8);
    }
    __syncthreads();
#pragma unroll
    for (int kk = 0; kk < 2; ++kk) {
      short8 af[2], bq[4];
#pragma unroll
      for (int i = 0; i < 2; ++i)
        af[i] = *(const short8*)&As[(wr * 32 + i * 16 + l16) * 64 + kk * 32 + lg * 8];
#pragma unroll
      for (int j = 0; j < 4; ++j)
        bq[j] = *(const short8*)&Bs[(wc * 64 + j * 16 + l16) * 64 + kk * 32 + lg * 8];
#pragma unroll
      for (int i = 0; i < 2; ++i)
#pragma unroll
        for (int j = 0; j < 4; ++j)
          acc[i][j] = __builtin_amdgcn_mfma_f32_16x16x32_bf16(af[i], bq[j], acc[i][j], 0, 0, 0);
    }
  }

  // ---- fused epilogue ----
  const int hg = bn * 2 + wc;   // global 64-wide head slot, uniform per wave
  if (hg >= 20) {               // V: cast + transposed store
    const int kvh = hg - 20;
#pragma unroll
    for (int i = 0; i < 2; ++i) {
      int row0 = bm * 64 + wr * 32 + i * 16 + lg * 4;
#pragma unroll
      for (int j = 0; j < 4; ++j) {
        int d = j * 16 + l16;
        ushort4 o = { f2bf(acc[i][j][0]), f2bf(acc[i][j][1]),
                      f2bf(acc[i][j][2]), f2bf(acc[i][j][3]) };
        *(ushort4*)(vtout + (size_t)(kvh * 64 + d) * S_LEN + row0) = o;
      }
    }
    return;
  }
  // Q/K: RMSNorm + RoPE
  const float* nw = (hg < 16) ? qw : kw;
  float wgt[4];
#pragma unroll
  for (int j = 0; j < 4; ++j) wgt[j] = nw[j * 16 + l16];
#pragma unroll
  for (int i = 0; i < 2; ++i) {
    int row0 = bm * 64 + wr * 32 + i * 16 + lg * 4;
    float qn[4][4];
#pragma unroll
    for (int r = 0; r < 4; ++r) {
      float ss = acc[i][0][r] * acc[i][0][r] + acc[i][1][r] * acc[i][1][r]
               + acc[i][2][r] * acc[i][2][r] + acc[i][3][r] * acc[i][3][r];
      ss += __shfl_xor(ss, 1);
      ss += __shfl_xor(ss, 2);
      ss += __shfl_xor(ss, 4);
      ss += __shfl_xor(ss, 8);
      float inv = rsqrtf(ss * (1.0f / 64.0f) + 1e-5f);
#pragma unroll
      for (int j = 0; j < 4; ++j) qn[j][r] = acc[i][j][r] * inv * wgt[j];
    }
#pragma unroll
    for (int j = 0; j < 4; ++j) {
      int d = j * 16 + l16;
#pragma unroll
      for (int r = 0; r < 4; ++r) {
        int row = row0 + r;
        float rot = (j < 2) ? -qn[j + 2][r] : qn[j - 2][r];   // rotate_half
        float o = qn[j][r] * cosb[row * 64 + d] + rot * sinb[row * 64 + d];
        if (hg < 16)
          qout[(size_t)row * HIDDEN + hg * 64 + d] = f2bf(o * QSCALE);
        else
          kout[((size_t)(hg - 16) * S_LEN + row) * 64 + d] = f2bf(o);
      }
    }
  }
}

// ---------------------------------------------------------------------------
// Kernel 4: C[M][N] = A[M][K] * B[N][K]^T — output projection (M=4096, N=1024).
// Flat grid 512, XCD-pinned.
// ---------------------------------------------------------------------------
__global__ __launch_bounds__(256) void k_gemm_bf16(
    const uint16_t* __restrict__ A, const uint16_t* __restrict__ B,
    float* __restrict__ C, int N, int K) {
  __shared__ uint16_t As[64 * 64];
  __shared__ uint16_t Bs[128 * 64];
  const int t = threadIdx.x;
  const int lane = t & 63, w = t >> 6;
  const int wr = w >> 1, wc = w & 1;
  const int l16 = lane & 15, lg = lane >> 4;
  const int bid = blockIdx.x;
  const int xcd = bid & 7, idx = bid >> 3;         // idx in [0,64)
  const int bm = xcd + 8 * (idx & 7);              // [0,64)
  const int bn = idx >> 3;                         // [0,8)
  const uint16_t* Ab = A + (size_t)bm * 64 * K;
  const uint16_t* Bb = B + (size_t)bn * 128 * K;
  f32x4 acc[2][4] = {};
  for (int k0 = 0; k0 < K; k0 += 64) {
    __syncthreads();
    {
      int row = t >> 3, c8 = (t & 7) << 3;
      gld_lds16(&As[t * 8], Ab + (size_t)row * K + k0 + c8);
      int t2 = t + 256, row2 = t2 >> 3, c82 = (t2 & 7) << 3;
      gld_lds16(&As[t2 * 8], Ab + (size_t)row2 * K + k0 + c82);
    }
#pragma unroll
    for (int it = 0; it < 4; ++it) {
      int idx2 = it * 256 + t;
      int row = idx2 >> 3, c8 = (idx2 & 7) << 3;
      gld_lds16(&Bs[idx2 * 8], Bb + (size_t)row * K + k0 + c8);
    }
    __syncthreads();
#pragma unroll
    for (int kk = 0; kk < 2; ++kk) {
      short8 af[2], bq[4];
#pragma unroll
      for (int i = 0; i < 2; ++i)
        af[i] = *(const short8*)&As[(wr * 32 + i * 16 + l16) * 64 + kk * 32 + lg * 8];
#pragma unroll
      for (int j = 0; j < 4; ++j)
        bq[j] = *(const short8*)&Bs[(wc * 64 + j * 16 + l16) * 64 + kk * 32 + lg * 8];
#pragma unroll
      for (int i = 0; i < 2; ++i)
#pragma unroll
        for (int j = 0; j < 4; ++j)
          acc[i][j] = __builtin_amdgcn_mfma_f32_16x16x32_bf16(af[i], bq[j], acc[i][j], 0, 0, 0);
    }
  }
#pragma unroll
  for (int i = 0; i < 2; ++i) {
    int row0 = bm * 64 + wr * 32 + i * 16 + lg * 4;
#pragma unroll
    for (int j = 0; j < 4; ++j) {
      int col = bn * 128 + wc * 64 + j * 16 + l16;
#pragma unroll
      for (int r = 0; r < 4; ++r)
        C[(size_t)(row0 + r) * N + col] = acc[i][j][r];
    }
  }
}

// ---------------------------------------------------------------------------
// Kernel 3: sliding-window flash attention.
// Best measured structure (round 9, 80.8us total): swapped QK^T 16x16,
// async gld_lds staging of K with XOR-swizzled [64][64] tiles (swizzle
// applied on the per-lane GLOBAL source address; reads XOR with l16&7),
// double-buffered K -> one barrier per tile; V LDS-staged (padded) via the
// same gld_lds path; P through per-wave LDS; fixed-max softmax
// (p = exp2(s), scores bounded by RMSNorm); T5 setprio.
// Flat grid 512, 512 threads = 8 waves; block = 64 q-rows x 2 heads of one
// kv group; hp = bid&7 (XCD-pinned), q0 reversed (long blocks first).
// NOTE (rounds 7-12): BK=128, 1-head blocks, V-direct-from-global,
// key-split 32x32 + in-register P all regressed or were null — the ~33us
// attn time is structural for this wave-geometry family.
// ---------------------------------------------------------------------------
__global__ __launch_bounds__(512) void k_attn(
    const uint16_t* __restrict__ qb,   // [S][HIDDEN], pre-scaled by QSCALE
    const uint16_t* __restrict__ kb,   // [KV][S][64]
    const uint16_t* __restrict__ vtb,  // [KV][64][S]
    const float* __restrict__ sinks,
    uint16_t* __restrict__ ao) {       // [S][HIDDEN]
  __shared__ uint16_t Kl[2][64][64];   // [buf][key][d], XOR-swizzled cols
  __shared__ uint16_t Vl[2][64][64];   // [buf][d][key], XOR-swizzled cols
  __shared__ uint16_t Pl[8][16][72];   // per-wave P: [q(16)][key(64)+pad]
  const int bid = blockIdx.x;
  const int hp = bid & 7;                  // head-pair
  const int q0 = (63 - (bid >> 3)) * 64;   // long blocks first
  const int kvh = hp >> 1;
  const int t = threadIdx.x;
  const int lane = t & 63, w = t >> 6;
  const int h = kvh * 4 + (hp & 1) * 2 + (w >> 2);
  const int wq = w & 3;
  const int l16 = lane & 15, lg = lane >> 4;
  const int qrow = q0 + wq * 16 + l16;     // this lane's q-row
  const int sw = l16 & 7;                  // read-side swizzle key

  // Q fragment, used as the B operand (n = l16 = q-row)
  short8 bq0, bq1;
  {
    const uint16_t* qp = qb + (size_t)qrow * HIDDEN + h * 64 + lg * 8;
    bq0 = *(const short8*)qp;
    bq1 = *(const short8*)(qp + 32);
  }
  float lsum = 0.f;
  f32x4 acc[4] = {};

  int kstart = q0 - WINDOW;
  if (kstart < 0) kstart = 0;

  // staging: thread t fills LDS row t>>3, col16 t&7; source col16 XOR'd.
  const int srow = t >> 3;
  const int scol = ((t & 7) ^ (srow & 7)) << 3;   // swizzled source col (elems)
  const uint16_t* kp = kb + ((size_t)kvh * S_LEN + srow) * 64 + scol;  // +k0*64
  const uint16_t* vp = vtb + ((size_t)kvh * 64 + srow) * S_LEN + scol; // +k0

  // prologue: stage first tile into buf 0
  gld_lds16(&Kl[0][0][0] + (size_t)t * 8, kp + (size_t)kstart * 64);
  gld_lds16(&Vl[0][0][0] + (size_t)t * 8, vp + kstart);
  __syncthreads();   // implicit vmcnt(0) drain: buf0 ready

  int ib = 0;
  for (int k0 = kstart; k0 <= q0; k0 += 64, ib ^= 1) {
    if (k0 + 64 <= q0) {   // async prefetch next tile; lands during compute
      gld_lds16(&Kl[ib ^ 1][0][0] + (size_t)t * 8, kp + (size_t)(k0 + 64) * 64);
      gld_lds16(&Vl[ib ^ 1][0][0] + (size_t)t * 8, vp + k0 + 64);
    }

    // S^T = K Q^T: D[m=key][n=q]; K read swizzled
    f32x4 st[4] = {};
    __builtin_amdgcn_s_setprio(1);
#pragma unroll
    for (int c = 0; c < 4; ++c) {
      short8 ak0 = *(const short8*)&Kl[ib][c * 16 + l16][(lg ^ sw) * 8];
      short8 ak1 = *(const short8*)&Kl[ib][c * 16 + l16][((lg + 4) ^ sw) * 8];
      st[c] = __builtin_amdgcn_mfma_f32_16x16x32_bf16(ak0, bq0, st[c], 0, 0, 0);
      st[c] = __builtin_amdgcn_mfma_f32_16x16x32_bf16(ak1, bq1, st[c], 0, 0, 0);
    }
    __builtin_amdgcn_s_setprio(0);

    // key = k0 + c*16 + lg*4 + r; q-row = qrow (lane-local). Mask edge tiles.
    float p[4][4];
    if (k0 == q0 || k0 == q0 - WINDOW) {
#pragma unroll
      for (int c = 0; c < 4; ++c) {
        int keyb = k0 + c * 16 + lg * 4;
#pragma unroll
        for (int r = 0; r < 4; ++r) {
          int key = keyb + r;
          bool ok = (key <= qrow) && (key + WINDOW > qrow);
          p[c][r] = ok ? exp2f(st[c][r]) : 0.f;
        }
      }
    } else {
#pragma unroll
      for (int c = 0; c < 4; ++c)
#pragma unroll
        for (int r = 0; r < 4; ++r)
          p[c][r] = exp2f(st[c][r]);
    }
#pragma unroll
    for (int c = 0; c < 4; ++c)
      lsum += (p[c][0] + p[c][1]) + (p[c][2] + p[c][3]);

    // pack P (keys consecutive in r) -> [q][key] LDS layout, 8B stores
#pragma unroll
    for (int c = 0; c < 4; ++c) {
      uint2 pw = { pk2(p[c][0], p[c][1]), pk2(p[c][2], p[c][3]) };
      *(uint2*)&Pl[w][l16][c * 16 + lg * 4] = pw;
    }
    asm volatile("s_waitcnt lgkmcnt(0)" ::: "memory");
    short8 pa0 = *(const short8*)&Pl[w][l16][lg * 8];
    short8 pa1 = *(const short8*)&Pl[w][l16][32 + lg * 8];
    __builtin_amdgcn_s_setprio(1);
#pragma unroll
    for (int dt = 0; dt < 4; ++dt) {
      short8 bv0 = *(const short8*)&Vl[ib][dt * 16 + l16][(lg ^ sw) * 8];
      short8 bv1 = *(const short8*)&Vl[ib][dt * 16 + l16][((lg + 4) ^ sw) * 8];
      acc[dt] = __builtin_amdgcn_mfma_f32_16x16x32_bf16(pa0, bv0, acc[dt], 0, 0, 0);
      acc[dt] = __builtin_amdgcn_mfma_f32_16x16x32_bf16(pa1, bv1, acc[dt], 0, 0, 0);
    }
    __builtin_amdgcn_s_setprio(0);

    // single barrier: all waves done reading buf[ib]; prefetch (vmcnt) drained
    __syncthreads();
  }

  // lsum: reduce across the 4 lg-groups (lanes sharing l16), add sink
  lsum += __shfl_xor(lsum, 16);
  lsum += __shfl_xor(lsum, 32);
  float sk = exp2f(sinks[h] * L2E);
  float inv = 1.0f / (lsum + sk);     // lane (l16,lg) holds inv for local row l16
  // acc rows are local row lg*4+r -> fetch inv from lane (lg*4+r)
#pragma unroll
  for (int r = 0; r < 4; ++r) {
    float rd = __shfl(inv, lg * 4 + r);
    int row = q0 + wq * 16 + lg * 4 + r;
#pragma unroll
    for (int dt = 0; dt < 4; ++dt)
      ao[(size_t)row * HIDDEN + h * 64 + dt * 16 + l16] = f2bf(acc[dt][r] * rd);
  }
}

// ---------------------------------------------------------------------------
// Launch. Workspace layout (~33 MB of d_ws):
//   [0,8M)    xb      bf16 x            [4096][1024]
//   [8,11M)   wqkvb   bf16 wq|wk|wv     [1536][1024]
//   [11,13M)  wob     bf16 wo           [1024][1024]
//   [13,21M)  qsc     bf16 q (scaled)   [4096][1024]
//   [21,23M)  kbf     bf16 k            [4][4096][64]
//   [23,25M)  vtb     bf16 v^T          [4][64][4096]
//   [25,33M)  aob     bf16 attn out     [4096][1024]
// ---------------------------------------------------------------------------
extern "C" void kernel_launch(void* const* d_in, const int* in_sizes, int n_in,
                              void* d_out, int out_size, void* d_ws, size_t ws_size,
                              hipStream_t stream) {
  const float* x     = (const float*)d_in[0];
  const float* cosb  = (const float*)d_in[1];
  const float* sinb  = (const float*)d_in[2];
  const float* wq    = (const float*)d_in[3];
  const float* wk    = (const float*)d_in[4];
  const float* wv    = (const float*)d_in[5];
  const float* wo    = (const float*)d_in[6];
  const float* qnw   = (const float*)d_in[7];
  const float* knw   = (const float*)d_in[8];
  const float* sinks = (const float*)d_in[9];
  float* out = (float*)d_out;

  char* ws = (char*)d_ws;
  uint16_t* xb    = (uint16_t*)(ws);
  uint16_t* wqkvb = (uint16_t*)(ws + (8ll  << 20));
  uint16_t* wob   = (uint16_t*)(ws + (11ll << 20));
  uint16_t* qsc   = (uint16_t*)(ws + (13ll << 20));
  uint16_t* kbf   = (uint16_t*)(ws + (21ll << 20));
  uint16_t* vtb   = (uint16_t*)(ws + (23ll << 20));
  uint16_t* aob   = (uint16_t*)(ws + (25ll << 20));

  k_tobf16  <<<6656, 256, 0, stream>>>(x, wq, wk, wv, wo, xb, wqkvb, wob);
  k_gemm_qkv<<<768, 256, 0, stream>>>(xb, wqkvb, cosb, sinb, qnw, knw,
                                      qsc, kbf, vtb);
  k_attn    <<<512, 512, 0, stream>>>(qsc, kbf, vtb, sinks, aob);
  k_gemm_bf16<<<512, 256, 0, stream>>>(aob, wob, out, 1024, 1024);
}

// Round 15
// 79.931 us; speedup vs baseline: 1.3765x; 1.0159x over previous
//
#include <hip/hip_runtime.h>
#include <hip/hip_bf16.h>
#include <stdint.h>

// Problem constants
#define S_LEN   4096
#define HIDDEN  1024
#define NHEAD   16
#define NKV     4
#define HD      64
#define WINDOW  512
#define L2E     1.4426950408889634f
#define QSCALE  (0.125f * L2E)

using short8   = __attribute__((ext_vector_type(8))) short;
using ushort8v = __attribute__((ext_vector_type(8))) unsigned short;
using f32x4    = __attribute__((ext_vector_type(4))) float;

// fp32 -> bf16, round-to-nearest-even
__device__ __forceinline__ uint16_t f2bf(float f) {
  uint32_t u = __builtin_bit_cast(uint32_t, f);
  u += 0x7fffu + ((u >> 16) & 1u);
  return (uint16_t)(u >> 16);
}
// round-to-nearest (ties up) — P values only (all >=0, bias ~2^-17)
__device__ __forceinline__ uint16_t f2bf_rn(float f) {
  uint32_t u = __builtin_bit_cast(uint32_t, f);
  return (uint16_t)((u + 0x8000u) >> 16);
}
__device__ __forceinline__ uint32_t pk2(float a, float b) {
  return (uint32_t)f2bf_rn(a) | ((uint32_t)f2bf_rn(b) << 16);
}

// async global->LDS, 16B per lane. LDS dest must be wave-uniform base + lane*16.
__device__ __forceinline__ void gld_lds16(void* lds, const void* g) {
  __builtin_amdgcn_global_load_lds(
      (const __attribute__((address_space(1))) char*)g,
      (__attribute__((address_space(3))) char*)lds, 16, 0, 0);
}

// ---------------------------------------------------------------------------
// Kernel 1: pack x, wq|wk|wv (concat rows), wo to bf16.
// 8 floats/thread (2x float4 -> one 16B store), grid 3328.
// Segment boundaries (float4 units) are all even, so a thread's pair never
// straddles a source switch.
// ---------------------------------------------------------------------------
__global__ __launch_bounds__(256) void k_tobf16(
    const float* __restrict__ x, const float* __restrict__ wq,
    const float* __restrict__ wk, const float* __restrict__ wv,
    const float* __restrict__ wo,
    uint16_t* __restrict__ xb, uint16_t* __restrict__ wqkvb,
    uint16_t* __restrict__ wob) {
  int i = blockIdx.x * 256 + threadIdx.x;  // 0..851967
  int p = i * 2;                           // first float4 index of the pair
  const float4* src; uint16_t* dst; int off;
  if (p < 1048576)      { src = (const float4*)x;  dst = xb;                off = p; }
  else if (p < 1310720) { src = (const float4*)wq; dst = wqkvb;             off = p - 1048576; }
  else if (p < 1376256) { src = (const float4*)wk; dst = wqkvb + 1024*1024; off = p - 1310720; }
  else if (p < 1441792) { src = (const float4*)wv; dst = wqkvb + 1280*1024; off = p - 1376256; }
  else                  { src = (const float4*)wo; dst = wob;               off = p - 1441792; }
  float4 a = src[off], b = src[off + 1];
  ushort8v o = { f2bf(a.x), f2bf(a.y), f2bf(a.z), f2bf(a.w),
                 f2bf(b.x), f2bf(b.y), f2bf(b.z), f2bf(b.w) };
  *(ushort8v*)(dst + (size_t)off * 4) = o;
}

// ---------------------------------------------------------------------------
// Kernel 2: QKV GEMM with fused RMSNorm + RoPE + cast + layout epilogue.
// BM=64, BN=128, BK=64; 4 waves in 2x2, wave tile 32x64 (acc[2][4]).
// Flat grid 768 with XCD-pinning swizzle.
// ---------------------------------------------------------------------------
__global__ __launch_bounds__(256) void k_gemm_qkv(
    const uint16_t* __restrict__ A, const uint16_t* __restrict__ B,
    const float* __restrict__ cosb, const float* __restrict__ sinb,
    const float* __restrict__ qw, const float* __restrict__ kw,
    uint16_t* __restrict__ qout, uint16_t* __restrict__ kout,
    uint16_t* __restrict__ vtout) {
  __shared__ uint16_t As[64 * 64];
  __shared__ uint16_t Bs[128 * 64];
  const int K = 1024;
  const int t = threadIdx.x;
  const int lane = t & 63, w = t >> 6;
  const int wr = w >> 1, wc = w & 1;
  const int l16 = lane & 15, lg = lane >> 4;
  const int bid = blockIdx.x;
  const int xcd = bid & 7, idx = bid >> 3;         // idx in [0,96)
  const int bm = xcd + 8 * (idx & 7);              // [0,64)
  const int bn = idx >> 3;                         // [0,12)
  const uint16_t* Ab = A + (size_t)bm * 64 * K;
  const uint16_t* Bb = B + (size_t)bn * 128 * K;
  f32x4 acc[2][4] = {};
  for (int k0 = 0; k0 < K; k0 += 64) {
    __syncthreads();
    {  // stage A: 64x64 = 512 16B-chunks -> 2/thread
      int row = t >> 3, c8 = (t & 7) << 3;
      gld_lds16(&As[t * 8], Ab + (size_t)row * K + k0 + c8);
      int t2 = t + 256, row2 = t2 >> 3, c82 = (t2 & 7) << 3;
      gld_lds16(&As[t2 * 8], Ab + (size_t)row2 * K + k0 + c82);
    }
#pragma unroll
    for (int it = 0; it < 4; ++it) {  // stage B: 128x64 -> 4/thread
      int idx2 = it * 256 + t;
      int row = idx2 >> 3, c8 = (idx2 & 7) << 3;
      gld_lds16(&Bs[idx2 * 8], Bb + (size_t)row * K + k0 + c8);
    }
    __syncthreads();
#pragma unroll
    for (int kk = 0; kk < 2; ++kk) {
      short8 af[2], bq[4];
#pragma unroll
      for (int i = 0; i < 2; ++i)
        af[i] = *(const short8*)&As[(wr * 32 + i * 16 + l16) * 64 + kk * 32 + lg * 8];
#pragma unroll
      for (int j = 0; j < 4; ++j)
        bq[j] = *(const short8*)&Bs[(wc * 64 + j * 16 + l16) * 64 + kk * 32 + lg * 8];
#pragma unroll
      for (int i = 0; i < 2; ++i)
#pragma unroll
        for (int j = 0; j < 4; ++j)
          acc[i][j] = __builtin_amdgcn_mfma_f32_16x16x32_bf16(af[i], bq[j], acc[i][j], 0, 0, 0);
    }
  }

  // ---- fused epilogue ----
  const int hg = bn * 2 + wc;   // global 64-wide head slot, uniform per wave
  if (hg >= 20) {               // V: cast + transposed store
    const int kvh = hg - 20;
#pragma unroll
    for (int i = 0; i < 2; ++i) {
      int row0 = bm * 64 + wr * 32 + i * 16 + lg * 4;
#pragma unroll
      for (int j = 0; j < 4; ++j) {
        int d = j * 16 + l16;
        ushort4 o = { f2bf(acc[i][j][0]), f2bf(acc[i][j][1]),
                      f2bf(acc[i][j][2]), f2bf(acc[i][j][3]) };
        *(ushort4*)(vtout + (size_t)(kvh * 64 + d) * S_LEN + row0) = o;
      }
    }
    return;
  }
  // Q/K: RMSNorm + RoPE
  const float* nw = (hg < 16) ? qw : kw;
  float wgt[4];
#pragma unroll
  for (int j = 0; j < 4; ++j) wgt[j] = nw[j * 16 + l16];
#pragma unroll
  for (int i = 0; i < 2; ++i) {
    int row0 = bm * 64 + wr * 32 + i * 16 + lg * 4;
    float qn[4][4];
#pragma unroll
    for (int r = 0; r < 4; ++r) {
      float ss = acc[i][0][r] * acc[i][0][r] + acc[i][1][r] * acc[i][1][r]
               + acc[i][2][r] * acc[i][2][r] + acc[i][3][r] * acc[i][3][r];
      ss += __shfl_xor(ss, 1);
      ss += __shfl_xor(ss, 2);
      ss += __shfl_xor(ss, 4);
      ss += __shfl_xor(ss, 8);
      float inv = rsqrtf(ss * (1.0f / 64.0f) + 1e-5f);
#pragma unroll
      for (int j = 0; j < 4; ++j) qn[j][r] = acc[i][j][r] * inv * wgt[j];
    }
#pragma unroll
    for (int j = 0; j < 4; ++j) {
      int d = j * 16 + l16;
#pragma unroll
      for (int r = 0; r < 4; ++r) {
        int row = row0 + r;
        float rot = (j < 2) ? -qn[j + 2][r] : qn[j - 2][r];   // rotate_half
        float o = qn[j][r] * cosb[row * 64 + d] + rot * sinb[row * 64 + d];
        if (hg < 16)
          qout[(size_t)row * HIDDEN + hg * 64 + d] = f2bf(o * QSCALE);
        else
          kout[((size_t)(hg - 16) * S_LEN + row) * 64 + d] = f2bf(o);
      }
    }
  }
}

// ---------------------------------------------------------------------------
// Kernel 4: C[M][N] = A[M][K] * B[N][K]^T — output projection (M=4096, N=1024).
// Flat grid 512, XCD-pinned.
// ---------------------------------------------------------------------------
__global__ __launch_bounds__(256) void k_gemm_bf16(
    const uint16_t* __restrict__ A, const uint16_t* __restrict__ B,
    float* __restrict__ C, int N, int K) {
  __shared__ uint16_t As[64 * 64];
  __shared__ uint16_t Bs[128 * 64];
  const int t = threadIdx.x;
  const int lane = t & 63, w = t >> 6;
  const int wr = w >> 1, wc = w & 1;
  const int l16 = lane & 15, lg = lane >> 4;
  const int bid = blockIdx.x;
  const int xcd = bid & 7, idx = bid >> 3;         // idx in [0,64)
  const int bm = xcd + 8 * (idx & 7);              // [0,64)
  const int bn = idx >> 3;                         // [0,8)
  const uint16_t* Ab = A + (size_t)bm * 64 * K;
  const uint16_t* Bb = B + (size_t)bn * 128 * K;
  f32x4 acc[2][4] = {};
  for (int k0 = 0; k0 < K; k0 += 64) {
    __syncthreads();
    {
      int row = t >> 3, c8 = (t & 7) << 3;
      gld_lds16(&As[t * 8], Ab + (size_t)row * K + k0 + c8);
      int t2 = t + 256, row2 = t2 >> 3, c82 = (t2 & 7) << 3;
      gld_lds16(&As[t2 * 8], Ab + (size_t)row2 * K + k0 + c82);
    }
#pragma unroll
    for (int it = 0; it < 4; ++it) {
      int idx2 = it * 256 + t;
      int row = idx2 >> 3, c8 = (idx2 & 7) << 3;
      gld_lds16(&Bs[idx2 * 8], Bb + (size_t)row * K + k0 + c8);
    }
    __syncthreads();
#pragma unroll
    for (int kk = 0; kk < 2; ++kk) {
      short8 af[2], bq[4];
#pragma unroll
      for (int i = 0; i < 2; ++i)
        af[i] = *(const short8*)&As[(wr * 32 + i * 16 + l16) * 64 + kk * 32 + lg * 8];
#pragma unroll
      for (int j = 0; j < 4; ++j)
        bq[j] = *(const short8*)&Bs[(wc * 64 + j * 16 + l16) * 64 + kk * 32 + lg * 8];
#pragma unroll
      for (int i = 0; i < 2; ++i)
#pragma unroll
        for (int j = 0; j < 4; ++j)
          acc[i][j] = __builtin_amdgcn_mfma_f32_16x16x32_bf16(af[i], bq[j], acc[i][j], 0, 0, 0);
    }
  }
#pragma unroll
  for (int i = 0; i < 2; ++i) {
    int row0 = bm * 64 + wr * 32 + i * 16 + lg * 4;
#pragma unroll
    for (int j = 0; j < 4; ++j) {
      int col = bn * 128 + wc * 64 + j * 16 + l16;
#pragma unroll
      for (int r = 0; r < 4; ++r)
        C[(size_t)(row0 + r) * N + col] = acc[i][j][r];
    }
  }
}

// ---------------------------------------------------------------------------
// Kernel 3: sliding-window flash attention (round-9 structure, setprio
// removed per m190: null-to-negative in barrier-lockstep wave groups).
// Swapped QK^T 16x16; async gld_lds staging with XOR-swizzled [64][64]
// tiles (swizzle on the per-lane GLOBAL source col; reads XOR with l16&7);
// double-buffered K/V -> one barrier per tile; P through per-wave LDS;
// fixed-max softmax (p = exp2(s), scores bounded by RMSNorm).
// Flat grid 512, 512 threads = 8 waves; block = 64 q-rows x 2 heads.
// ---------------------------------------------------------------------------
__global__ __launch_bounds__(512) void k_attn(
    const uint16_t* __restrict__ qb,   // [S][HIDDEN], pre-scaled by QSCALE
    const uint16_t* __restrict__ kb,   // [KV][S][64]
    const uint16_t* __restrict__ vtb,  // [KV][64][S]
    const float* __restrict__ sinks,
    uint16_t* __restrict__ ao) {       // [S][HIDDEN]
  __shared__ uint16_t Kl[2][64][64];   // [buf][key][d], XOR-swizzled cols
  __shared__ uint16_t Vl[2][64][64];   // [buf][d][key], XOR-swizzled cols
  __shared__ uint16_t Pl[8][16][72];   // per-wave P: [q(16)][key(64)+pad]
  const int bid = blockIdx.x;
  const int hp = bid & 7;                  // head-pair
  const int q0 = (63 - (bid >> 3)) * 64;   // long blocks first
  const int kvh = hp >> 1;
  const int t = threadIdx.x;
  const int lane = t & 63, w = t >> 6;
  const int h = kvh * 4 + (hp & 1) * 2 + (w >> 2);
  const int wq = w & 3;
  const int l16 = lane & 15, lg = lane >> 4;
  const int qrow = q0 + wq * 16 + l16;     // this lane's q-row
  const int sw = l16 & 7;                  // read-side swizzle key

  // Q fragment, used as the B operand (n = l16 = q-row)
  short8 bq0, bq1;
  {
    const uint16_t* qp = qb + (size_t)qrow * HIDDEN + h * 64 + lg * 8;
    bq0 = *(const short8*)qp;
    bq1 = *(const short8*)(qp + 32);
  }
  float lsum = 0.f;
  f32x4 acc[4] = {};

  int kstart = q0 - WINDOW;
  if (kstart < 0) kstart = 0;

  // staging: thread t fills LDS row t>>3, col16 t&7; source col16 XOR'd.
  const int srow = t >> 3;
  const int scol = ((t & 7) ^ (srow & 7)) << 3;   // swizzled source col (elems)
  const uint16_t* kp = kb + ((size_t)kvh * S_LEN + srow) * 64 + scol;  // +k0*64
  const uint16_t* vp = vtb + ((size_t)kvh * 64 + srow) * S_LEN + scol; // +k0

  // prologue: stage first tile into buf 0
  gld_lds16(&Kl[0][0][0] + (size_t)t * 8, kp + (size_t)kstart * 64);
  gld_lds16(&Vl[0][0][0] + (size_t)t * 8, vp + kstart);
  __syncthreads();   // implicit vmcnt(0) drain: buf0 ready

  int ib = 0;
  for (int k0 = kstart; k0 <= q0; k0 += 64, ib ^= 1) {
    if (k0 + 64 <= q0) {   // async prefetch next tile; lands during compute
      gld_lds16(&Kl[ib ^ 1][0][0] + (size_t)t * 8, kp + (size_t)(k0 + 64) * 64);
      gld_lds16(&Vl[ib ^ 1][0][0] + (size_t)t * 8, vp + k0 + 64);
    }

    // S^T = K Q^T: D[m=key][n=q]; K read swizzled
    f32x4 st[4] = {};
#pragma unroll
    for (int c = 0; c < 4; ++c) {
      short8 ak0 = *(const short8*)&Kl[ib][c * 16 + l16][(lg ^ sw) * 8];
      short8 ak1 = *(const short8*)&Kl[ib][c * 16 + l16][((lg + 4) ^ sw) * 8];
      st[c] = __builtin_amdgcn_mfma_f32_16x16x32_bf16(ak0, bq0, st[c], 0, 0, 0);
      st[c] = __builtin_amdgcn_mfma_f32_16x16x32_bf16(ak1, bq1, st[c], 0, 0, 0);
    }

    // key = k0 + c*16 + lg*4 + r; q-row = qrow (lane-local). Mask edge tiles.
    float p[4][4];
    if (k0 == q0 || k0 == q0 - WINDOW) {
#pragma unroll
      for (int c = 0; c < 4; ++c) {
        int keyb = k0 + c * 16 + lg * 4;
#pragma unroll
        for (int r = 0; r < 4; ++r) {
          int key = keyb + r;
          bool ok = (key <= qrow) && (key + WINDOW > qrow);
          p[c][r] = ok ? exp2f(st[c][r]) : 0.f;
        }
      }
    } else {
#pragma unroll
      for (int c = 0; c < 4; ++c)
#pragma unroll
        for (int r = 0; r < 4; ++r)
          p[c][r] = exp2f(st[c][r]);
    }
#pragma unroll
    for (int c = 0; c < 4; ++c)
      lsum += (p[c][0] + p[c][1]) + (p[c][2] + p[c][3]);

    // pack P (keys consecutive in r) -> [q][key] LDS layout, 8B stores
#pragma unroll
    for (int c = 0; c < 4; ++c) {
      uint2 pw = { pk2(p[c][0], p[c][1]), pk2(p[c][2], p[c][3]) };
      *(uint2*)&Pl[w][l16][c * 16 + lg * 4] = pw;
    }
    asm volatile("s_waitcnt lgkmcnt(0)" ::: "memory");
    short8 pa0 = *(const short8*)&Pl[w][l16][lg * 8];
    short8 pa1 = *(const short8*)&Pl[w][l16][32 + lg * 8];
#pragma unroll
    for (int dt = 0; dt < 4; ++dt) {
      short8 bv0 = *(const short8*)&Vl[ib][dt * 16 + l16][(lg ^ sw) * 8];
      short8 bv1 = *(const short8*)&Vl[ib][dt * 16 + l16][((lg + 4) ^ sw) * 8];
      acc[dt] = __builtin_amdgcn_mfma_f32_16x16x32_bf16(pa0, bv0, acc[dt], 0, 0, 0);
      acc[dt] = __builtin_amdgcn_mfma_f32_16x16x32_bf16(pa1, bv1, acc[dt], 0, 0, 0);
    }

    // single barrier: all waves done reading buf[ib]; prefetch (vmcnt) drained
    __syncthreads();
  }

  // lsum: reduce across the 4 lg-groups (lanes sharing l16), add sink
  lsum += __shfl_xor(lsum, 16);
  lsum += __shfl_xor(lsum, 32);
  float sk = exp2f(sinks[h] * L2E);
  float inv = 1.0f / (lsum + sk);     // lane (l16,lg) holds inv for local row l16
  // acc rows are local row lg*4+r -> fetch inv from lane (lg*4+r)
#pragma unroll
  for (int r = 0; r < 4; ++r) {
    float rd = __shfl(inv, lg * 4 + r);
    int row = q0 + wq * 16 + lg * 4 + r;
#pragma unroll
    for (int dt = 0; dt < 4; ++dt)
      ao[(size_t)row * HIDDEN + h * 64 + dt * 16 + l16] = f2bf(acc[dt][r] * rd);
  }
}

// ---------------------------------------------------------------------------
// Launch. Workspace layout (~33 MB of d_ws):
//   [0,8M)    xb      bf16 x            [4096][1024]
//   [8,11M)   wqkvb   bf16 wq|wk|wv     [1536][1024]
//   [11,13M)  wob     bf16 wo           [1024][1024]
//   [13,21M)  qsc     bf16 q (scaled)   [4096][1024]
//   [21,23M)  kbf     bf16 k            [4][4096][64]
//   [23,25M)  vtb     bf16 v^T          [4][64][4096]
//   [25,33M)  aob     bf16 attn out     [4096][1024]
// ---------------------------------------------------------------------------
extern "C" void kernel_launch(void* const* d_in, const int* in_sizes, int n_in,
                              void* d_out, int out_size, void* d_ws, size_t ws_size,
                              hipStream_t stream) {
  const float* x     = (const float*)d_in[0];
  const float* cosb  = (const float*)d_in[1];
  const float* sinb  = (const float*)d_in[2];
  const float* wq    = (const float*)d_in[3];
  const float* wk    = (const float*)d_in[4];
  const float* wv    = (const float*)d_in[5];
  const float* wo    = (const float*)d_in[6];
  const float* qnw   = (const float*)d_in[7];
  const float* knw   = (const float*)d_in[8];
  const float* sinks = (const float*)d_in[9];
  float* out = (float*)d_out;

  char* ws = (char*)d_ws;
  uint16_t* xb    = (uint16_t*)(ws);
  uint16_t* wqkvb = (uint16_t*)(ws + (8ll  << 20));
  uint16_t* wob   = (uint16_t*)(ws + (11ll << 20));
  uint16_t* qsc   = (uint16_t*)(ws + (13ll << 20));
  uint16_t* kbf   = (uint16_t*)(ws + (21ll << 20));
  uint16_t* vtb   = (uint16_t*)(ws + (23ll << 20));
  uint16_t* aob   = (uint16_t*)(ws + (25ll << 20));

  k_tobf16  <<<3328, 256, 0, stream>>>(x, wq, wk, wv, wo, xb, wqkvb, wob);
  k_gemm_qkv<<<768, 256, 0, stream>>>(xb, wqkvb, cosb, sinb, qnw, knw,
                                      qsc, kbf, vtb);
  k_attn    <<<512, 512, 0, stream>>>(qsc, kbf, vtb, sinks, aob);
  k_gemm_bf16<<<512, 256, 0, stream>>>(aob, wob, out, 1024, 1024);
}

// Round 16
// 79.820 us; speedup vs baseline: 1.3784x; 1.0014x over previous
//
#include <hip/hip_runtime.h>
#include <hip/hip_bf16.h>
#include <stdint.h>

// Problem constants
#define S_LEN   4096
#define HIDDEN  1024
#define NHEAD   16
#define NKV     4
#define HD      64
#define WINDOW  512
#define L2E     1.4426950408889634f
#define QSCALE  (0.125f * L2E)

using short8   = __attribute__((ext_vector_type(8))) short;
using ushort8v = __attribute__((ext_vector_type(8))) unsigned short;
using f32x4    = __attribute__((ext_vector_type(4))) float;

// fp32 -> bf16, round-to-nearest-even
__device__ __forceinline__ uint16_t f2bf(float f) {
  uint32_t u = __builtin_bit_cast(uint32_t, f);
  u += 0x7fffu + ((u >> 16) & 1u);
  return (uint16_t)(u >> 16);
}
// round-to-nearest (ties up) — P values only (all >=0, bias ~2^-17)
__device__ __forceinline__ uint16_t f2bf_rn(float f) {
  uint32_t u = __builtin_bit_cast(uint32_t, f);
  return (uint16_t)((u + 0x8000u) >> 16);
}
__device__ __forceinline__ uint32_t pk2(float a, float b) {
  return (uint32_t)f2bf_rn(a) | ((uint32_t)f2bf_rn(b) << 16);
}

// async global->LDS, 16B per lane. LDS dest must be wave-uniform base + lane*16.
__device__ __forceinline__ void gld_lds16(void* lds, const void* g) {
  __builtin_amdgcn_global_load_lds(
      (const __attribute__((address_space(1))) char*)g,
      (__attribute__((address_space(3))) char*)lds, 16, 0, 0);
}

// ---------------------------------------------------------------------------
// Kernel 1: pack x, wq|wk|wv (concat rows), wo to bf16.
// 8 floats/thread (2x float4 -> one 16B store), grid 3328.
// Segment boundaries (float4 units) are all even, so a thread's pair never
// straddles a source switch.
// ---------------------------------------------------------------------------
__global__ __launch_bounds__(256) void k_tobf16(
    const float* __restrict__ x, const float* __restrict__ wq,
    const float* __restrict__ wk, const float* __restrict__ wv,
    const float* __restrict__ wo,
    uint16_t* __restrict__ xb, uint16_t* __restrict__ wqkvb,
    uint16_t* __restrict__ wob) {
  int i = blockIdx.x * 256 + threadIdx.x;  // 0..851967
  int p = i * 2;                           // first float4 index of the pair
  const float4* src; uint16_t* dst; int off;
  if (p < 1048576)      { src = (const float4*)x;  dst = xb;                off = p; }
  else if (p < 1310720) { src = (const float4*)wq; dst = wqkvb;             off = p - 1048576; }
  else if (p < 1376256) { src = (const float4*)wk; dst = wqkvb + 1024*1024; off = p - 1310720; }
  else if (p < 1441792) { src = (const float4*)wv; dst = wqkvb + 1280*1024; off = p - 1376256; }
  else                  { src = (const float4*)wo; dst = wob;               off = p - 1441792; }
  float4 a = src[off], b = src[off + 1];
  ushort8v o = { f2bf(a.x), f2bf(a.y), f2bf(a.z), f2bf(a.w),
                 f2bf(b.x), f2bf(b.y), f2bf(b.z), f2bf(b.w) };
  *(ushort8v*)(dst + (size_t)off * 4) = o;
}

// ---------------------------------------------------------------------------
// Kernel 2: QKV GEMM with fused RMSNorm + RoPE + cast + layout epilogue.
// BM=64, BN=128, BK=64; 4 waves in 2x2, wave tile 32x64 (acc[2][4]).
// Flat grid 768 with XCD-pinning swizzle.
// ---------------------------------------------------------------------------
__global__ __launch_bounds__(256) void k_gemm_qkv(
    const uint16_t* __restrict__ A, const uint16_t* __restrict__ B,
    const float* __restrict__ cosb, const float* __restrict__ sinb,
    const float* __restrict__ qw, const float* __restrict__ kw,
    uint16_t* __restrict__ qout, uint16_t* __restrict__ kout,
    uint16_t* __restrict__ vtout) {
  __shared__ uint16_t As[64 * 64];
  __shared__ uint16_t Bs[128 * 64];
  const int K = 1024;
  const int t = threadIdx.x;
  const int lane = t & 63, w = t >> 6;
  const int wr = w >> 1, wc = w & 1;
  const int l16 = lane & 15, lg = lane >> 4;
  const int bid = blockIdx.x;
  const int xcd = bid & 7, idx = bid >> 3;         // idx in [0,96)
  const int bm = xcd + 8 * (idx & 7);              // [0,64)
  const int bn = idx >> 3;                         // [0,12)
  const uint16_t* Ab = A + (size_t)bm * 64 * K;
  const uint16_t* Bb = B + (size_t)bn * 128 * K;
  f32x4 acc[2][4] = {};
  for (int k0 = 0; k0 < K; k0 += 64) {
    __syncthreads();
    {  // stage A: 64x64 = 512 16B-chunks -> 2/thread
      int row = t >> 3, c8 = (t & 7) << 3;
      gld_lds16(&As[t * 8], Ab + (size_t)row * K + k0 + c8);
      int t2 = t + 256, row2 = t2 >> 3, c82 = (t2 & 7) << 3;
      gld_lds16(&As[t2 * 8], Ab + (size_t)row2 * K + k0 + c82);
    }
#pragma unroll
    for (int it = 0; it < 4; ++it) {  // stage B: 128x64 -> 4/thread
      int idx2 = it * 256 + t;
      int row = idx2 >> 3, c8 = (idx2 & 7) << 3;
      gld_lds16(&Bs[idx2 * 8], Bb + (size_t)row * K + k0 + c8);
    }
    __syncthreads();
#pragma unroll
    for (int kk = 0; kk < 2; ++kk) {
      short8 af[2], bq[4];
#pragma unroll
      for (int i = 0; i < 2; ++i)
        af[i] = *(const short8*)&As[(wr * 32 + i * 16 + l16) * 64 + kk * 32 + lg * 8];
#pragma unroll
      for (int j = 0; j < 4; ++j)
        bq[j] = *(const short8*)&Bs[(wc * 64 + j * 16 + l16) * 64 + kk * 32 + lg * 8];
#pragma unroll
      for (int i = 0; i < 2; ++i)
#pragma unroll
        for (int j = 0; j < 4; ++j)
          acc[i][j] = __builtin_amdgcn_mfma_f32_16x16x32_bf16(af[i], bq[j], acc[i][j], 0, 0, 0);
    }
  }

  // ---- fused epilogue ----
  const int hg = bn * 2 + wc;   // global 64-wide head slot, uniform per wave
  if (hg >= 20) {               // V: cast + transposed store
    const int kvh = hg - 20;
#pragma unroll
    for (int i = 0; i < 2; ++i) {
      int row0 = bm * 64 + wr * 32 + i * 16 + lg * 4;
#pragma unroll
      for (int j = 0; j < 4; ++j) {
        int d = j * 16 + l16;
        ushort4 o = { f2bf(acc[i][j][0]), f2bf(acc[i][j][1]),
                      f2bf(acc[i][j][2]), f2bf(acc[i][j][3]) };
        *(ushort4*)(vtout + (size_t)(kvh * 64 + d) * S_LEN + row0) = o;
      }
    }
    return;
  }
  // Q/K: RMSNorm + RoPE
  const float* nw = (hg < 16) ? qw : kw;
  float wgt[4];
#pragma unroll
  for (int j = 0; j < 4; ++j) wgt[j] = nw[j * 16 + l16];
#pragma unroll
  for (int i = 0; i < 2; ++i) {
    int row0 = bm * 64 + wr * 32 + i * 16 + lg * 4;
    float qn[4][4];
#pragma unroll
    for (int r = 0; r < 4; ++r) {
      float ss = acc[i][0][r] * acc[i][0][r] + acc[i][1][r] * acc[i][1][r]
               + acc[i][2][r] * acc[i][2][r] + acc[i][3][r] * acc[i][3][r];
      ss += __shfl_xor(ss, 1);
      ss += __shfl_xor(ss, 2);
      ss += __shfl_xor(ss, 4);
      ss += __shfl_xor(ss, 8);
      float inv = rsqrtf(ss * (1.0f / 64.0f) + 1e-5f);
#pragma unroll
      for (int j = 0; j < 4; ++j) qn[j][r] = acc[i][j][r] * inv * wgt[j];
    }
#pragma unroll
    for (int j = 0; j < 4; ++j) {
      int d = j * 16 + l16;
#pragma unroll
      for (int r = 0; r < 4; ++r) {
        int row = row0 + r;
        float rot = (j < 2) ? -qn[j + 2][r] : qn[j - 2][r];   // rotate_half
        float o = qn[j][r] * cosb[row * 64 + d] + rot * sinb[row * 64 + d];
        if (hg < 16)
          qout[(size_t)row * HIDDEN + hg * 64 + d] = f2bf(o * QSCALE);
        else
          kout[((size_t)(hg - 16) * S_LEN + row) * 64 + d] = f2bf(o);
      }
    }
  }
}

// ---------------------------------------------------------------------------
// Kernel 4: C[M][N] = A[M][K] * B[N][K]^T — output projection (M=4096, N=1024).
// Flat grid 512, XCD-pinned.
// ---------------------------------------------------------------------------
__global__ __launch_bounds__(256) void k_gemm_bf16(
    const uint16_t* __restrict__ A, const uint16_t* __restrict__ B,
    float* __restrict__ C, int N, int K) {
  __shared__ uint16_t As[64 * 64];
  __shared__ uint16_t Bs[128 * 64];
  const int t = threadIdx.x;
  const int lane = t & 63, w = t >> 6;
  const int wr = w >> 1, wc = w & 1;
  const int l16 = lane & 15, lg = lane >> 4;
  const int bid = blockIdx.x;
  const int xcd = bid & 7, idx = bid >> 3;         // idx in [0,64)
  const int bm = xcd + 8 * (idx & 7);              // [0,64)
  const int bn = idx >> 3;                         // [0,8)
  const uint16_t* Ab = A + (size_t)bm * 64 * K;
  const uint16_t* Bb = B + (size_t)bn * 128 * K;
  f32x4 acc[2][4] = {};
  for (int k0 = 0; k0 < K; k0 += 64) {
    __syncthreads();
    {
      int row = t >> 3, c8 = (t & 7) << 3;
      gld_lds16(&As[t * 8], Ab + (size_t)row * K + k0 + c8);
      int t2 = t + 256, row2 = t2 >> 3, c82 = (t2 & 7) << 3;
      gld_lds16(&As[t2 * 8], Ab + (size_t)row2 * K + k0 + c82);
    }
#pragma unroll
    for (int it = 0; it < 4; ++it) {
      int idx2 = it * 256 + t;
      int row = idx2 >> 3, c8 = (idx2 & 7) << 3;
      gld_lds16(&Bs[idx2 * 8], Bb + (size_t)row * K + k0 + c8);
    }
    __syncthreads();
#pragma unroll
    for (int kk = 0; kk < 2; ++kk) {
      short8 af[2], bq[4];
#pragma unroll
      for (int i = 0; i < 2; ++i)
        af[i] = *(const short8*)&As[(wr * 32 + i * 16 + l16) * 64 + kk * 32 + lg * 8];
#pragma unroll
      for (int j = 0; j < 4; ++j)
        bq[j] = *(const short8*)&Bs[(wc * 64 + j * 16 + l16) * 64 + kk * 32 + lg * 8];
#pragma unroll
      for (int i = 0; i < 2; ++i)
#pragma unroll
        for (int j = 0; j < 4; ++j)
          acc[i][j] = __builtin_amdgcn_mfma_f32_16x16x32_bf16(af[i], bq[j], acc[i][j], 0, 0, 0);
    }
  }
#pragma unroll
  for (int i = 0; i < 2; ++i) {
    int row0 = bm * 64 + wr * 32 + i * 16 + lg * 4;
#pragma unroll
    for (int j = 0; j < 4; ++j) {
      int col = bn * 128 + wc * 64 + j * 16 + l16;
#pragma unroll
      for (int r = 0; r < 4; ++r)
        C[(size_t)(row0 + r) * N + col] = acc[i][j][r];
    }
  }
}

// ---------------------------------------------------------------------------
// Kernel 3: sliding-window flash attention (round-9 structure, setprio
// removed per m190: null-to-negative in barrier-lockstep wave groups).
// Swapped QK^T 16x16; async gld_lds staging with XOR-swizzled [64][64]
// tiles (swizzle on the per-lane GLOBAL source col; reads XOR with l16&7);
// double-buffered K/V -> one barrier per tile; P through per-wave LDS;
// fixed-max softmax (p = exp2(s), scores bounded by RMSNorm).
// Flat grid 512, 512 threads = 8 waves; block = 64 q-rows x 2 heads.
// ---------------------------------------------------------------------------
__global__ __launch_bounds__(512) void k_attn(
    const uint16_t* __restrict__ qb,   // [S][HIDDEN], pre-scaled by QSCALE
    const uint16_t* __restrict__ kb,   // [KV][S][64]
    const uint16_t* __restrict__ vtb,  // [KV][64][S]
    const float* __restrict__ sinks,
    uint16_t* __restrict__ ao) {       // [S][HIDDEN]
  __shared__ uint16_t Kl[2][64][64];   // [buf][key][d], XOR-swizzled cols
  __shared__ uint16_t Vl[2][64][64];   // [buf][d][key], XOR-swizzled cols
  __shared__ uint16_t Pl[8][16][72];   // per-wave P: [q(16)][key(64)+pad]
  const int bid = blockIdx.x;
  const int hp = bid & 7;                  // head-pair
  const int q0 = (63 - (bid >> 3)) * 64;   // long blocks first
  const int kvh = hp >> 1;
  const int t = threadIdx.x;
  const int lane = t & 63, w = t >> 6;
  const int h = kvh * 4 + (hp & 1) * 2 + (w >> 2);
  const int wq = w & 3;
  const int l16 = lane & 15, lg = lane >> 4;
  const int qrow = q0 + wq * 16 + l16;     // this lane's q-row
  const int sw = l16 & 7;                  // read-side swizzle key

  // Q fragment, used as the B operand (n = l16 = q-row)
  short8 bq0, bq1;
  {
    const uint16_t* qp = qb + (size_t)qrow * HIDDEN + h * 64 + lg * 8;
    bq0 = *(const short8*)qp;
    bq1 = *(const short8*)(qp + 32);
  }
  float lsum = 0.f;
  f32x4 acc[4] = {};

  int kstart = q0 - WINDOW;
  if (kstart < 0) kstart = 0;

  // staging: thread t fills LDS row t>>3, col16 t&7; source col16 XOR'd.
  const int srow = t >> 3;
  const int scol = ((t & 7) ^ (srow & 7)) << 3;   // swizzled source col (elems)
  const uint16_t* kp = kb + ((size_t)kvh * S_LEN + srow) * 64 + scol;  // +k0*64
  const uint16_t* vp = vtb + ((size_t)kvh * 64 + srow) * S_LEN + scol; // +k0

  // prologue: stage first tile into buf 0
  gld_lds16(&Kl[0][0][0] + (size_t)t * 8, kp + (size_t)kstart * 64);
  gld_lds16(&Vl[0][0][0] + (size_t)t * 8, vp + kstart);
  __syncthreads();   // implicit vmcnt(0) drain: buf0 ready

  int ib = 0;
  for (int k0 = kstart; k0 <= q0; k0 += 64, ib ^= 1) {
    if (k0 + 64 <= q0) {   // async prefetch next tile; lands during compute
      gld_lds16(&Kl[ib ^ 1][0][0] + (size_t)t * 8, kp + (size_t)(k0 + 64) * 64);
      gld_lds16(&Vl[ib ^ 1][0][0] + (size_t)t * 8, vp + k0 + 64);
    }

    // S^T = K Q^T: D[m=key][n=q]; K read swizzled
    f32x4 st[4] = {};
#pragma unroll
    for (int c = 0; c < 4; ++c) {
      short8 ak0 = *(const short8*)&Kl[ib][c * 16 + l16][(lg ^ sw) * 8];
      short8 ak1 = *(const short8*)&Kl[ib][c * 16 + l16][((lg + 4) ^ sw) * 8];
      st[c] = __builtin_amdgcn_mfma_f32_16x16x32_bf16(ak0, bq0, st[c], 0, 0, 0);
      st[c] = __builtin_amdgcn_mfma_f32_16x16x32_bf16(ak1, bq1, st[c], 0, 0, 0);
    }

    // key = k0 + c*16 + lg*4 + r; q-row = qrow (lane-local). Mask edge tiles.
    float p[4][4];
    if (k0 == q0 || k0 == q0 - WINDOW) {
#pragma unroll
      for (int c = 0; c < 4; ++c) {
        int keyb = k0 + c * 16 + lg * 4;
#pragma unroll
        for (int r = 0; r < 4; ++r) {
          int key = keyb + r;
          bool ok = (key <= qrow) && (key + WINDOW > qrow);
          p[c][r] = ok ? exp2f(st[c][r]) : 0.f;
        }
      }
    } else {
#pragma unroll
      for (int c = 0; c < 4; ++c)
#pragma unroll
        for (int r = 0; r < 4; ++r)
          p[c][r] = exp2f(st[c][r]);
    }
#pragma unroll
    for (int c = 0; c < 4; ++c)
      lsum += (p[c][0] + p[c][1]) + (p[c][2] + p[c][3]);

    // pack P (keys consecutive in r) -> [q][key] LDS layout, 8B stores
#pragma unroll
    for (int c = 0; c < 4; ++c) {
      uint2 pw = { pk2(p[c][0], p[c][1]), pk2(p[c][2], p[c][3]) };
      *(uint2*)&Pl[w][l16][c * 16 + lg * 4] = pw;
    }
    asm volatile("s_waitcnt lgkmcnt(0)" ::: "memory");
    short8 pa0 = *(const short8*)&Pl[w][l16][lg * 8];
    short8 pa1 = *(const short8*)&Pl[w][l16][32 + lg * 8];
#pragma unroll
    for (int dt = 0; dt < 4; ++dt) {
      short8 bv0 = *(const short8*)&Vl[ib][dt * 16 + l16][(lg ^ sw) * 8];
      short8 bv1 = *(const short8*)&Vl[ib][dt * 16 + l16][((lg + 4) ^ sw) * 8];
      acc[dt] = __builtin_amdgcn_mfma_f32_16x16x32_bf16(pa0, bv0, acc[dt], 0, 0, 0);
      acc[dt] = __builtin_amdgcn_mfma_f32_16x16x32_bf16(pa1, bv1, acc[dt], 0, 0, 0);
    }

    // single barrier: all waves done reading buf[ib]; prefetch (vmcnt) drained
    __syncthreads();
  }

  // lsum: reduce across the 4 lg-groups (lanes sharing l16), add sink
  lsum += __shfl_xor(lsum, 16);
  lsum += __shfl_xor(lsum, 32);
  float sk = exp2f(sinks[h] * L2E);
  float inv = 1.0f / (lsum + sk);     // lane (l16,lg) holds inv for local row l16
  // acc rows are local row lg*4+r -> fetch inv from lane (lg*4+r)
#pragma unroll
  for (int r = 0; r < 4; ++r) {
    float rd = __shfl(inv, lg * 4 + r);
    int row = q0 + wq * 16 + lg * 4 + r;
#pragma unroll
    for (int dt = 0; dt < 4; ++dt)
      ao[(size_t)row * HIDDEN + h * 64 + dt * 16 + l16] = f2bf(acc[dt][r] * rd);
  }
}

// ---------------------------------------------------------------------------
// Launch. Workspace layout (~33 MB of d_ws):
//   [0,8M)    xb      bf16 x            [4096][1024]
//   [8,11M)   wqkvb   bf16 wq|wk|wv     [1536][1024]
//   [11,13M)  wob     bf16 wo           [1024][1024]
//   [13,21M)  qsc     bf16 q (scaled)   [4096][1024]
//   [21,23M)  kbf     bf16 k            [4][4096][64]
//   [23,25M)  vtb     bf16 v^T          [4][64][4096]
//   [25,33M)  aob     bf16 attn out     [4096][1024]
// ---------------------------------------------------------------------------
extern "C" void kernel_launch(void* const* d_in, const int* in_sizes, int n_in,
                              void* d_out, int out_size, void* d_ws, size_t ws_size,
                              hipStream_t stream) {
  const float* x     = (const float*)d_in[0];
  const float* cosb  = (const float*)d_in[1];
  const float* sinb  = (const float*)d_in[2];
  const float* wq    = (const float*)d_in[3];
  const float* wk    = (const float*)d_in[4];
  const float* wv    = (const float*)d_in[5];
  const float* wo    = (const float*)d_in[6];
  const float* qnw   = (const float*)d_in[7];
  const float* knw   = (const float*)d_in[8];
  const float* sinks = (const float*)d_in[9];
  float* out = (float*)d_out;

  char* ws = (char*)d_ws;
  uint16_t* xb    = (uint16_t*)(ws);
  uint16_t* wqkvb = (uint16_t*)(ws + (8ll  << 20));
  uint16_t* wob   = (uint16_t*)(ws + (11ll << 20));
  uint16_t* qsc   = (uint16_t*)(ws + (13ll << 20));
  uint16_t* kbf   = (uint16_t*)(ws + (21ll << 20));
  uint16_t* vtb   = (uint16_t*)(ws + (23ll << 20));
  uint16_t* aob   = (uint16_t*)(ws + (25ll << 20));

  k_tobf16  <<<3328, 256, 0, stream>>>(x, wq, wk, wv, wo, xb, wqkvb, wob);
  k_gemm_qkv<<<768, 256, 0, stream>>>(xb, wqkvb, cosb, sinb, qnw, knw,
                                      qsc, kbf, vtb);
  k_attn    <<<512, 512, 0, stream>>>(qsc, kbf, vtb, sinks, aob);
  k_gemm_bf16<<<512, 256, 0, stream>>>(aob, wob, out, 1024, 1024);
}

// Round 17
// 79.717 us; speedup vs baseline: 1.3802x; 1.0013x over previous
//
#include <hip/hip_runtime.h>
#include <hip/hip_bf16.h>
#include <stdint.h>

// Problem constants
#define S_LEN   4096
#define HIDDEN  1024
#define NHEAD   16
#define NKV     4
#define HD      64
#define WINDOW  512
#define L2E     1.4426950408889634f
#define QSCALE  (0.125f * L2E)

using short8   = __attribute__((ext_vector_type(8))) short;
using ushort8v = __attribute__((ext_vector_type(8))) unsigned short;
using f32x4    = __attribute__((ext_vector_type(4))) float;

// fp32 -> bf16, round-to-nearest-even
__device__ __forceinline__ uint16_t f2bf(float f) {
  uint32_t u = __builtin_bit_cast(uint32_t, f);
  u += 0x7fffu + ((u >> 16) & 1u);
  return (uint16_t)(u >> 16);
}
// round-to-nearest (ties up) — P values only (all >=0, bias ~2^-17)
__device__ __forceinline__ uint16_t f2bf_rn(float f) {
  uint32_t u = __builtin_bit_cast(uint32_t, f);
  return (uint16_t)((u + 0x8000u) >> 16);
}
__device__ __forceinline__ uint32_t pk2(float a, float b) {
  return (uint32_t)f2bf_rn(a) | ((uint32_t)f2bf_rn(b) << 16);
}

// async global->LDS, 16B per lane. LDS dest must be wave-uniform base + lane*16.
__device__ __forceinline__ void gld_lds16(void* lds, const void* g) {
  __builtin_amdgcn_global_load_lds(
      (const __attribute__((address_space(1))) char*)g,
      (__attribute__((address_space(3))) char*)lds, 16, 0, 0);
}

// ---------------------------------------------------------------------------
// Kernel 1: pack x, wq|wk|wv (concat rows), wo to bf16.
// 8 floats/thread (2x float4 -> one 16B store), grid 3328.
// Segment boundaries (float4 units) are all even, so a thread's pair never
// straddles a source switch.
// ---------------------------------------------------------------------------
__global__ __launch_bounds__(256) void k_tobf16(
    const float* __restrict__ x, const float* __restrict__ wq,
    const float* __restrict__ wk, const float* __restrict__ wv,
    const float* __restrict__ wo,
    uint16_t* __restrict__ xb, uint16_t* __restrict__ wqkvb,
    uint16_t* __restrict__ wob) {
  int i = blockIdx.x * 256 + threadIdx.x;  // 0..851967
  int p = i * 2;                           // first float4 index of the pair
  const float4* src; uint16_t* dst; int off;
  if (p < 1048576)      { src = (const float4*)x;  dst = xb;                off = p; }
  else if (p < 1310720) { src = (const float4*)wq; dst = wqkvb;             off = p - 1048576; }
  else if (p < 1376256) { src = (const float4*)wk; dst = wqkvb + 1024*1024; off = p - 1310720; }
  else if (p < 1441792) { src = (const float4*)wv; dst = wqkvb + 1280*1024; off = p - 1376256; }
  else                  { src = (const float4*)wo; dst = wob;               off = p - 1441792; }
  float4 a = src[off], b = src[off + 1];
  ushort8v o = { f2bf(a.x), f2bf(a.y), f2bf(a.z), f2bf(a.w),
                 f2bf(b.x), f2bf(b.y), f2bf(b.z), f2bf(b.w) };
  *(ushort8v*)(dst + (size_t)off * 4) = o;
}

// ---------------------------------------------------------------------------
// Kernel 2: QKV GEMM with fused RMSNorm + RoPE + cast + layout epilogue.
// BM=64, BN=128, BK=64; 4 waves in 2x2, wave tile 32x64 (acc[2][4]).
// Flat grid 768 with XCD-pinning swizzle.
// ---------------------------------------------------------------------------
__global__ __launch_bounds__(256) void k_gemm_qkv(
    const uint16_t* __restrict__ A, const uint16_t* __restrict__ B,
    const float* __restrict__ cosb, const float* __restrict__ sinb,
    const float* __restrict__ qw, const float* __restrict__ kw,
    uint16_t* __restrict__ qout, uint16_t* __restrict__ kout,
    uint16_t* __restrict__ vtout) {
  __shared__ uint16_t As[64 * 64];
  __shared__ uint16_t Bs[128 * 64];
  const int K = 1024;
  const int t = threadIdx.x;
  const int lane = t & 63, w = t >> 6;
  const int wr = w >> 1, wc = w & 1;
  const int l16 = lane & 15, lg = lane >> 4;
  const int bid = blockIdx.x;
  const int xcd = bid & 7, idx = bid >> 3;         // idx in [0,96)
  const int bm = xcd + 8 * (idx & 7);              // [0,64)
  const int bn = idx >> 3;                         // [0,12)
  const uint16_t* Ab = A + (size_t)bm * 64 * K;
  const uint16_t* Bb = B + (size_t)bn * 128 * K;
  f32x4 acc[2][4] = {};
  for (int k0 = 0; k0 < K; k0 += 64) {
    __syncthreads();
    {  // stage A: 64x64 = 512 16B-chunks -> 2/thread
      int row = t >> 3, c8 = (t & 7) << 3;
      gld_lds16(&As[t * 8], Ab + (size_t)row * K + k0 + c8);
      int t2 = t + 256, row2 = t2 >> 3, c82 = (t2 & 7) << 3;
      gld_lds16(&As[t2 * 8], Ab + (size_t)row2 * K + k0 + c82);
    }
#pragma unroll
    for (int it = 0; it < 4; ++it) {  // stage B: 128x64 -> 4/thread
      int idx2 = it * 256 + t;
      int row = idx2 >> 3, c8 = (idx2 & 7) << 3;
      gld_lds16(&Bs[idx2 * 8], Bb + (size_t)row * K + k0 + c8);
    }
    __syncthreads();
#pragma unroll
    for (int kk = 0; kk < 2; ++kk) {
      short8 af[2], bq[4];
#pragma unroll
      for (int i = 0; i < 2; ++i)
        af[i] = *(const short8*)&As[(wr * 32 + i * 16 + l16) * 64 + kk * 32 + lg * 8];
#pragma unroll
      for (int j = 0; j < 4; ++j)
        bq[j] = *(const short8*)&Bs[(wc * 64 + j * 16 + l16) * 64 + kk * 32 + lg * 8];
#pragma unroll
      for (int i = 0; i < 2; ++i)
#pragma unroll
        for (int j = 0; j < 4; ++j)
          acc[i][j] = __builtin_amdgcn_mfma_f32_16x16x32_bf16(af[i], bq[j], acc[i][j], 0, 0, 0);
    }
  }

  // ---- fused epilogue ----
  const int hg = bn * 2 + wc;   // global 64-wide head slot, uniform per wave
  if (hg >= 20) {               // V: cast + transposed store
    const int kvh = hg - 20;
#pragma unroll
    for (int i = 0; i < 2; ++i) {
      int row0 = bm * 64 + wr * 32 + i * 16 + lg * 4;
#pragma unroll
      for (int j = 0; j < 4; ++j) {
        int d = j * 16 + l16;
        ushort4 o = { f2bf(acc[i][j][0]), f2bf(acc[i][j][1]),
                      f2bf(acc[i][j][2]), f2bf(acc[i][j][3]) };
        *(ushort4*)(vtout + (size_t)(kvh * 64 + d) * S_LEN + row0) = o;
      }
    }
    return;
  }
  // Q/K: RMSNorm + RoPE
  const float* nw = (hg < 16) ? qw : kw;
  float wgt[4];
#pragma unroll
  for (int j = 0; j < 4; ++j) wgt[j] = nw[j * 16 + l16];
#pragma unroll
  for (int i = 0; i < 2; ++i) {
    int row0 = bm * 64 + wr * 32 + i * 16 + lg * 4;
    float qn[4][4];
#pragma unroll
    for (int r = 0; r < 4; ++r) {
      float ss = acc[i][0][r] * acc[i][0][r] + acc[i][1][r] * acc[i][1][r]
               + acc[i][2][r] * acc[i][2][r] + acc[i][3][r] * acc[i][3][r];
      ss += __shfl_xor(ss, 1);
      ss += __shfl_xor(ss, 2);
      ss += __shfl_xor(ss, 4);
      ss += __shfl_xor(ss, 8);
      float inv = rsqrtf(ss * (1.0f / 64.0f) + 1e-5f);
#pragma unroll
      for (int j = 0; j < 4; ++j) qn[j][r] = acc[i][j][r] * inv * wgt[j];
    }
#pragma unroll
    for (int j = 0; j < 4; ++j) {
      int d = j * 16 + l16;
#pragma unroll
      for (int r = 0; r < 4; ++r) {
        int row = row0 + r;
        float rot = (j < 2) ? -qn[j + 2][r] : qn[j - 2][r];   // rotate_half
        float o = qn[j][r] * cosb[row * 64 + d] + rot * sinb[row * 64 + d];
        if (hg < 16)
          qout[(size_t)row * HIDDEN + hg * 64 + d] = f2bf(o * QSCALE);
        else
          kout[((size_t)(hg - 16) * S_LEN + row) * 64 + d] = f2bf(o);
      }
    }
  }
}

// ---------------------------------------------------------------------------
// Kernel 4: C[M][N] = A[M][K] * B[N][K]^T — output projection (M=4096, N=1024).
// Flat grid 512, XCD-pinned.
// ---------------------------------------------------------------------------
__global__ __launch_bounds__(256) void k_gemm_bf16(
    const uint16_t* __restrict__ A, const uint16_t* __restrict__ B,
    float* __restrict__ C, int N, int K) {
  __shared__ uint16_t As[64 * 64];
  __shared__ uint16_t Bs[128 * 64];
  const int t = threadIdx.x;
  const int lane = t & 63, w = t >> 6;
  const int wr = w >> 1, wc = w & 1;
  const int l16 = lane & 15, lg = lane >> 4;
  const int bid = blockIdx.x;
  const int xcd = bid & 7, idx = bid >> 3;         // idx in [0,64)
  const int bm = xcd + 8 * (idx & 7);              // [0,64)
  const int bn = idx >> 3;                         // [0,8)
  const uint16_t* Ab = A + (size_t)bm * 64 * K;
  const uint16_t* Bb = B + (size_t)bn * 128 * K;
  f32x4 acc[2][4] = {};
  for (int k0 = 0; k0 < K; k0 += 64) {
    __syncthreads();
    {
      int row = t >> 3, c8 = (t & 7) << 3;
      gld_lds16(&As[t * 8], Ab + (size_t)row * K + k0 + c8);
      int t2 = t + 256, row2 = t2 >> 3, c82 = (t2 & 7) << 3;
      gld_lds16(&As[t2 * 8], Ab + (size_t)row2 * K + k0 + c82);
    }
#pragma unroll
    for (int it = 0; it < 4; ++it) {
      int idx2 = it * 256 + t;
      int row = idx2 >> 3, c8 = (idx2 & 7) << 3;
      gld_lds16(&Bs[idx2 * 8], Bb + (size_t)row * K + k0 + c8);
    }
    __syncthreads();
#pragma unroll
    for (int kk = 0; kk < 2; ++kk) {
      short8 af[2], bq[4];
#pragma unroll
      for (int i = 0; i < 2; ++i)
        af[i] = *(const short8*)&As[(wr * 32 + i * 16 + l16) * 64 + kk * 32 + lg * 8];
#pragma unroll
      for (int j = 0; j < 4; ++j)
        bq[j] = *(const short8*)&Bs[(wc * 64 + j * 16 + l16) * 64 + kk * 32 + lg * 8];
#pragma unroll
      for (int i = 0; i < 2; ++i)
#pragma unroll
        for (int j = 0; j < 4; ++j)
          acc[i][j] = __builtin_amdgcn_mfma_f32_16x16x32_bf16(af[i], bq[j], acc[i][j], 0, 0, 0);
    }
  }
#pragma unroll
  for (int i = 0; i < 2; ++i) {
    int row0 = bm * 64 + wr * 32 + i * 16 + lg * 4;
#pragma unroll
    for (int j = 0; j < 4; ++j) {
      int col = bn * 128 + wc * 64 + j * 16 + l16;
#pragma unroll
      for (int r = 0; r < 4; ++r)
        C[(size_t)(row0 + r) * N + col] = acc[i][j][r];
    }
  }
}

// ---------------------------------------------------------------------------
// Kernel 3: sliding-window flash attention (round-9 structure, setprio
// removed per m190: null-to-negative in barrier-lockstep wave groups).
// Swapped QK^T 16x16; async gld_lds staging with XOR-swizzled [64][64]
// tiles (swizzle on the per-lane GLOBAL source col; reads XOR with l16&7);
// double-buffered K/V -> one barrier per tile; P through per-wave LDS;
// fixed-max softmax (p = exp2(s), scores bounded by RMSNorm).
// Flat grid 512, 512 threads = 8 waves; block = 64 q-rows x 2 heads.
// ---------------------------------------------------------------------------
__global__ __launch_bounds__(512) void k_attn(
    const uint16_t* __restrict__ qb,   // [S][HIDDEN], pre-scaled by QSCALE
    const uint16_t* __restrict__ kb,   // [KV][S][64]
    const uint16_t* __restrict__ vtb,  // [KV][64][S]
    const float* __restrict__ sinks,
    uint16_t* __restrict__ ao) {       // [S][HIDDEN]
  __shared__ uint16_t Kl[2][64][64];   // [buf][key][d], XOR-swizzled cols
  __shared__ uint16_t Vl[2][64][64];   // [buf][d][key], XOR-swizzled cols
  __shared__ uint16_t Pl[8][16][72];   // per-wave P: [q(16)][key(64)+pad]
  const int bid = blockIdx.x;
  const int hp = bid & 7;                  // head-pair
  const int q0 = (63 - (bid >> 3)) * 64;   // long blocks first
  const int kvh = hp >> 1;
  const int t = threadIdx.x;
  const int lane = t & 63, w = t >> 6;
  const int h = kvh * 4 + (hp & 1) * 2 + (w >> 2);
  const int wq = w & 3;
  const int l16 = lane & 15, lg = lane >> 4;
  const int qrow = q0 + wq * 16 + l16;     // this lane's q-row
  const int sw = l16 & 7;                  // read-side swizzle key

  // Q fragment, used as the B operand (n = l16 = q-row)
  short8 bq0, bq1;
  {
    const uint16_t* qp = qb + (size_t)qrow * HIDDEN + h * 64 + lg * 8;
    bq0 = *(const short8*)qp;
    bq1 = *(const short8*)(qp + 32);
  }
  float lsum = 0.f;
  f32x4 acc[4] = {};

  int kstart = q0 - WINDOW;
  if (kstart < 0) kstart = 0;

  // staging: thread t fills LDS row t>>3, col16 t&7; source col16 XOR'd.
  const int srow = t >> 3;
  const int scol = ((t & 7) ^ (srow & 7)) << 3;   // swizzled source col (elems)
  const uint16_t* kp = kb + ((size_t)kvh * S_LEN + srow) * 64 + scol;  // +k0*64
  const uint16_t* vp = vtb + ((size_t)kvh * 64 + srow) * S_LEN + scol; // +k0

  // prologue: stage first tile into buf 0
  gld_lds16(&Kl[0][0][0] + (size_t)t * 8, kp + (size_t)kstart * 64);
  gld_lds16(&Vl[0][0][0] + (size_t)t * 8, vp + kstart);
  __syncthreads();   // implicit vmcnt(0) drain: buf0 ready

  int ib = 0;
  for (int k0 = kstart; k0 <= q0; k0 += 64, ib ^= 1) {
    if (k0 + 64 <= q0) {   // async prefetch next tile; lands during compute
      gld_lds16(&Kl[ib ^ 1][0][0] + (size_t)t * 8, kp + (size_t)(k0 + 64) * 64);
      gld_lds16(&Vl[ib ^ 1][0][0] + (size_t)t * 8, vp + k0 + 64);
    }

    // S^T = K Q^T: D[m=key][n=q]; K read swizzled
    f32x4 st[4] = {};
#pragma unroll
    for (int c = 0; c < 4; ++c) {
      short8 ak0 = *(const short8*)&Kl[ib][c * 16 + l16][(lg ^ sw) * 8];
      short8 ak1 = *(const short8*)&Kl[ib][c * 16 + l16][((lg + 4) ^ sw) * 8];
      st[c] = __builtin_amdgcn_mfma_f32_16x16x32_bf16(ak0, bq0, st[c], 0, 0, 0);
      st[c] = __builtin_amdgcn_mfma_f32_16x16x32_bf16(ak1, bq1, st[c], 0, 0, 0);
    }

    // key = k0 + c*16 + lg*4 + r; q-row = qrow (lane-local). Mask edge tiles.
    float p[4][4];
    if (k0 == q0 || k0 == q0 - WINDOW) {
#pragma unroll
      for (int c = 0; c < 4; ++c) {
        int keyb = k0 + c * 16 + lg * 4;
#pragma unroll
        for (int r = 0; r < 4; ++r) {
          int key = keyb + r;
          bool ok = (key <= qrow) && (key + WINDOW > qrow);
          p[c][r] = ok ? exp2f(st[c][r]) : 0.f;
        }
      }
    } else {
#pragma unroll
      for (int c = 0; c < 4; ++c)
#pragma unroll
        for (int r = 0; r < 4; ++r)
          p[c][r] = exp2f(st[c][r]);
    }
#pragma unroll
    for (int c = 0; c < 4; ++c)
      lsum += (p[c][0] + p[c][1]) + (p[c][2] + p[c][3]);

    // pack P (keys consecutive in r) -> [q][key] LDS layout, 8B stores
#pragma unroll
    for (int c = 0; c < 4; ++c) {
      uint2 pw = { pk2(p[c][0], p[c][1]), pk2(p[c][2], p[c][3]) };
      *(uint2*)&Pl[w][l16][c * 16 + lg * 4] = pw;
    }
    asm volatile("s_waitcnt lgkmcnt(0)" ::: "memory");
    short8 pa0 = *(const short8*)&Pl[w][l16][lg * 8];
    short8 pa1 = *(const short8*)&Pl[w][l16][32 + lg * 8];
#pragma unroll
    for (int dt = 0; dt < 4; ++dt) {
      short8 bv0 = *(const short8*)&Vl[ib][dt * 16 + l16][(lg ^ sw) * 8];
      short8 bv1 = *(const short8*)&Vl[ib][dt * 16 + l16][((lg + 4) ^ sw) * 8];
      acc[dt] = __builtin_amdgcn_mfma_f32_16x16x32_bf16(pa0, bv0, acc[dt], 0, 0, 0);
      acc[dt] = __builtin_amdgcn_mfma_f32_16x16x32_bf16(pa1, bv1, acc[dt], 0, 0, 0);
    }

    // single barrier: all waves done reading buf[ib]; prefetch (vmcnt) drained
    __syncthreads();
  }

  // lsum: reduce across the 4 lg-groups (lanes sharing l16), add sink
  lsum += __shfl_xor(lsum, 16);
  lsum += __shfl_xor(lsum, 32);
  float sk = exp2f(sinks[h] * L2E);
  float inv = 1.0f / (lsum + sk);     // lane (l16,lg) holds inv for local row l16
  // acc rows are local row lg*4+r -> fetch inv from lane (lg*4+r)
#pragma unroll
  for (int r = 0; r < 4; ++r) {
    float rd = __shfl(inv, lg * 4 + r);
    int row = q0 + wq * 16 + lg * 4 + r;
#pragma unroll
    for (int dt = 0; dt < 4; ++dt)
      ao[(size_t)row * HIDDEN + h * 64 + dt * 16 + l16] = f2bf(acc[dt][r] * rd);
  }
}

// ---------------------------------------------------------------------------
// Launch. Workspace layout (~33 MB of d_ws):
//   [0,8M)    xb      bf16 x            [4096][1024]
//   [8,11M)   wqkvb   bf16 wq|wk|wv     [1536][1024]
//   [11,13M)  wob     bf16 wo           [1024][1024]
//   [13,21M)  qsc     bf16 q (scaled)   [4096][1024]
//   [21,23M)  kbf     bf16 k            [4][4096][64]
//   [23,25M)  vtb     bf16 v^T          [4][64][4096]
//   [25,33M)  aob     bf16 attn out     [4096][1024]
// ---------------------------------------------------------------------------
extern "C" void kernel_launch(void* const* d_in, const int* in_sizes, int n_in,
                              void* d_out, int out_size, void* d_ws, size_t ws_size,
                              hipStream_t stream) {
  const float* x     = (const float*)d_in[0];
  const float* cosb  = (const float*)d_in[1];
  const float* sinb  = (const float*)d_in[2];
  const float* wq    = (const float*)d_in[3];
  const float* wk    = (const float*)d_in[4];
  const float* wv    = (const float*)d_in[5];
  const float* wo    = (const float*)d_in[6];
  const float* qnw   = (const float*)d_in[7];
  const float* knw   = (const float*)d_in[8];
  const float* sinks = (const float*)d_in[9];
  float* out = (float*)d_out;

  char* ws = (char*)d_ws;
  uint16_t* xb    = (uint16_t*)(ws);
  uint16_t* wqkvb = (uint16_t*)(ws + (8ll  << 20));
  uint16_t* wob   = (uint16_t*)(ws + (11ll << 20));
  uint16_t* qsc   = (uint16_t*)(ws + (13ll << 20));
  uint16_t* kbf   = (uint16_t*)(ws + (21ll << 20));
  uint16_t* vtb   = (uint16_t*)(ws + (23ll << 20));
  uint16_t* aob   = (uint16_t*)(ws + (25ll << 20));

  k_tobf16  <<<3328, 256, 0, stream>>>(x, wq, wk, wv, wo, xb, wqkvb, wob);
  k_gemm_qkv<<<768, 256, 0, stream>>>(xb, wqkvb, cosb, sinb, qnw, knw,
                                      qsc, kbf, vtb);
  k_attn    <<<512, 512, 0, stream>>>(qsc, kbf, vtb, sinks, aob);
  k_gemm_bf16<<<512, 256, 0, stream>>>(aob, wob, out, 1024, 1024);
}